// Round 6
// baseline (442.469 us; speedup 1.0000x reference)
//
#include <hip/hip_runtime.h>

#define NN 50000
#define NBGRAPH 512
#define DIN 768
#define DHID 256
#define DOUT 128

typedef unsigned short ushort_t;
typedef __attribute__((ext_vector_type(8))) short bf16x8;
typedef __attribute__((ext_vector_type(4))) float f32x4;
typedef _Float16 f16_t;
typedef __attribute__((ext_vector_type(8))) _Float16 f16x8;

__device__ __forceinline__ float lrelu(float v) { return v > 0.f ? v : 0.2f * v; }

__device__ __forceinline__ ushort_t f2bf(float f) {
  unsigned int u = __builtin_bit_cast(unsigned int, f);
  u += 0x7fffu + ((u >> 16) & 1u);
  return (ushort_t)(u >> 16);
}
__device__ __forceinline__ float h2f_u(ushort_t u) { return (float)__builtin_bit_cast(f16_t, u); }
__device__ __forceinline__ ushort_t f2h_u(float f) { return __builtin_bit_cast(ushort_t, (f16_t)f); }

__device__ __forceinline__ void fmah8(float* acc, float al, f16x8 v) {
#pragma unroll
  for (int q = 0; q < 8; ++q) acc[q] += al * (float)v[q];
}

__device__ __forceinline__ float sel_h(int h, float q0, float q1, float q2, float q3) {
  float lo = (h & 1) ? q1 : q0;
  float hi = (h & 1) ? q3 : q2;
  return (h & 2) ? hi : lo;
}

// ---------------- CSR build ----------------
__global__ void k_zero2(int* __restrict__ a, int* __restrict__ b, int n) {
  int i = blockIdx.x * blockDim.x + threadIdx.x;
  if (i < n) { a[i] = 0; b[i] = 0; }
}

__global__ void k_hist(const int* __restrict__ ei, int* __restrict__ deg, int E, int Etot) {
  int e = blockIdx.x * blockDim.x + threadIdx.x;
  if (e >= Etot) return;
  int dst = (e < E) ? ei[e] : (e - E);
  atomicAdd(&deg[dst], 1);
}

__global__ __launch_bounds__(1024) void k_scan1(const int* __restrict__ deg, int* __restrict__ off,
                                                int* __restrict__ bsum, int n) {
  __shared__ int wsum[16];
  int tid = threadIdx.x, lane = tid & 63, w = tid >> 6;
  int i = blockIdx.x * 1024 + tid;
  int v = (i < n) ? deg[i] : 0;
  int x = v;
#pragma unroll
  for (int d = 1; d < 64; d <<= 1) { int t = __shfl_up(x, d); if (lane >= d) x += t; }
  if (lane == 63) wsum[w] = x;
  __syncthreads();
  if (tid < 16) {
    int y = wsum[tid];
#pragma unroll
    for (int d = 1; d < 16; d <<= 1) { int t = __shfl_up(y, d); if (tid >= d) y += t; }
    wsum[tid] = y;
  }
  __syncthreads();
  int base = (w > 0) ? wsum[w - 1] : 0;
  if (i < n) off[i] = base + x - v;
  if (tid == 1023) bsum[blockIdx.x] = wsum[15];
}

__global__ void k_scan2(int* __restrict__ bsum, int* __restrict__ off, int nb, int n) {
  int lane = threadIdx.x;
  int v = (lane < nb) ? bsum[lane] : 0;
  int x = v;
#pragma unroll
  for (int d = 1; d < 64; d <<= 1) { int t = __shfl_up(x, d); if (lane >= d) x += t; }
  if (lane < nb) bsum[lane] = x - v;
  if (lane == 63) off[n] = x;
}

__global__ void k_scan3(int* __restrict__ off, const int* __restrict__ bsum, int n) {
  int i = blockIdx.x * blockDim.x + threadIdx.x;
  if (i < n) off[i] += bsum[i >> 10];
}

__global__ void k_scatter(const int* __restrict__ ei, const int* __restrict__ off,
                          int* __restrict__ cur, int* __restrict__ csr, int E, int Etot) {
  int e = blockIdx.x * blockDim.x + threadIdx.x;
  if (e >= Etot) return;
  int dst, src;
  if (e < E) { dst = ei[e]; src = ei[E + e]; }
  else       { dst = src = e - E; }
  int p = atomicAdd(&cur[dst], 1);
  csr[off[dst] + p] = src;
}

// ---------------- roots / segments ----------------
__global__ void k_segstart(const int* __restrict__ batch, int* __restrict__ segstart, int n, int b_cnt) {
  int b = blockIdx.x * blockDim.x + threadIdx.x;
  if (b > b_cnt) return;
  int lo = 0, hi = n;
  while (lo < hi) { int mid = (lo + hi) >> 1; if (batch[mid] < b) lo = mid + 1; else hi = mid; }
  segstart[b] = lo;
}

__global__ void k_rootn(const int* __restrict__ batch, const int* __restrict__ segstart,
                        int* __restrict__ rootn, int n) {
  int i = blockIdx.x * blockDim.x + threadIdx.x;
  if (i < n) rootn[i] = segstart[batch[i]];
}

// ---------------- weight transpose+cast (bf16 for MFMA) ----------------
__global__ void k_prepW(const float* __restrict__ W, ushort_t* __restrict__ Wt, int K, int N) {
  int id = blockIdx.x * blockDim.x + threadIdx.x;
  if (id >= K * N) return;
  int n = id / K, k = id - n * K;
  Wt[(size_t)n * K + k] = f2bf(W[(size_t)k * N + n]);
}

// ---------------- MFMA GEMM1: H1h = fp16( bf16(x) @ bf16(W1) ) ----------------
#define LDT 40
__global__ __launch_bounds__(256) void k_gemm1m(const float* __restrict__ A,
                                                const ushort_t* __restrict__ Bt,
                                                ushort_t* __restrict__ C) {
  const int K = DIN, NC = DHID;
  __shared__ __align__(16) ushort_t As[128 * LDT];
  __shared__ __align__(16) ushort_t Bs[128 * LDT];
  const int tid = threadIdx.x;
  const int bm = blockIdx.x * 128;
  const int bn = blockIdx.y * 128;
  const int row = tid >> 1, half = tid & 1;
  const int arow = bm + row;
  const int wid = tid >> 6, lane = tid & 63;
  const int wr = (wid >> 1) * 64, wc = (wid & 1) * 64;
  const int fr = lane & 15, fg = lane >> 4;
  f32x4 acc[4][4] = {};

  for (int k0 = 0; k0 < K; k0 += 32) {
    {
      const int p = row * LDT + half * 16;
      if (arow < NN) {
        const float4* src = (const float4*)&A[(size_t)arow * K + k0 + half * 16];
#pragma unroll
        for (int i = 0; i < 4; ++i) {
          float4 v = src[i];
          ushort4 w;
          w.x = f2bf(v.x); w.y = f2bf(v.y); w.z = f2bf(v.z); w.w = f2bf(v.w);
          *(ushort4*)&As[p + i * 4] = w;
        }
      } else {
        ushort4 z = {0, 0, 0, 0};
#pragma unroll
        for (int i = 0; i < 4; ++i) *(ushort4*)&As[p + i * 4] = z;
      }
    }
#pragma unroll
    for (int i = 0; i < 2; ++i) {
      int c2 = tid + i * 256;
      int br = c2 >> 2, bq = c2 & 3;
      uint4 v = *(const uint4*)&Bt[(size_t)(bn + br) * K + k0 + bq * 8];
      *(uint4*)&Bs[br * LDT + bq * 8] = v;
    }
    __syncthreads();
    bf16x8 af[4], bfr[4];
#pragma unroll
    for (int m = 0; m < 4; ++m) af[m] = *(const bf16x8*)&As[(wr + m * 16 + fr) * LDT + fg * 8];
#pragma unroll
    for (int n = 0; n < 4; ++n) bfr[n] = *(const bf16x8*)&Bs[(wc + n * 16 + fr) * LDT + fg * 8];
#pragma unroll
    for (int m = 0; m < 4; ++m)
#pragma unroll
      for (int n = 0; n < 4; ++n)
        acc[m][n] = __builtin_amdgcn_mfma_f32_16x16x32_bf16(af[m], bfr[n], acc[m][n], 0, 0, 0);
    __syncthreads();
  }
#pragma unroll
  for (int m = 0; m < 4; ++m)
#pragma unroll
    for (int n = 0; n < 4; ++n)
#pragma unroll
      for (int j = 0; j < 4; ++j) {
        int r = bm + wr + m * 16 + fg * 4 + j;
        if (r < NN) C[(size_t)r * NC + bn + wc + n * 16 + fr] = f2h_u(acc[m][n][j]);
      }
}

// ---------------- MFMA GEMM2: H2h = fp16( bf16(relu(concat(OUT1, x[root]))) @ bf16(W2) ) ----------------
__global__ __launch_bounds__(256) void k_gemm2m(const float* __restrict__ OUT1,
                                                const float* __restrict__ X,
                                                const int* __restrict__ rootn,
                                                const ushort_t* __restrict__ Bt,
                                                ushort_t* __restrict__ C) {
  const int K = DHID + DIN, NC = DOUT;
  __shared__ __align__(16) ushort_t As[128 * LDT];
  __shared__ __align__(16) ushort_t Bs[128 * LDT];
  const int tid = threadIdx.x;
  const int bm = blockIdx.x * 128;
  const int row = tid >> 1, half = tid & 1;
  const int arow = bm + row;
  const int rn = (arow < NN) ? rootn[arow] : 0;
  const int wid = tid >> 6, lane = tid & 63;
  const int wr = (wid >> 1) * 64, wc = (wid & 1) * 64;
  const int fr = lane & 15, fg = lane >> 4;
  f32x4 acc[4][4] = {};

  for (int k0 = 0; k0 < K; k0 += 32) {
    {
      const int p = row * LDT + half * 16;
      const int kk = k0 + half * 16;
      if (arow < NN) {
        const float4* src = (kk < DHID)
            ? (const float4*)&OUT1[(size_t)arow * DHID + kk]
            : (const float4*)&X[(size_t)rn * DIN + (kk - DHID)];
#pragma unroll
        for (int i = 0; i < 4; ++i) {
          float4 v = src[i];
          ushort4 w;
          w.x = f2bf(fmaxf(v.x, 0.f)); w.y = f2bf(fmaxf(v.y, 0.f));
          w.z = f2bf(fmaxf(v.z, 0.f)); w.w = f2bf(fmaxf(v.w, 0.f));
          *(ushort4*)&As[p + i * 4] = w;
        }
      } else {
        ushort4 z = {0, 0, 0, 0};
#pragma unroll
        for (int i = 0; i < 4; ++i) *(ushort4*)&As[p + i * 4] = z;
      }
    }
#pragma unroll
    for (int i = 0; i < 2; ++i) {
      int c2 = tid + i * 256;
      int br = c2 >> 2, bq = c2 & 3;
      uint4 v = *(const uint4*)&Bt[(size_t)br * K + k0 + bq * 8];
      *(uint4*)&Bs[br * LDT + bq * 8] = v;
    }
    __syncthreads();
    bf16x8 af[4], bfr[4];
#pragma unroll
    for (int m = 0; m < 4; ++m) af[m] = *(const bf16x8*)&As[(wr + m * 16 + fr) * LDT + fg * 8];
#pragma unroll
    for (int n = 0; n < 4; ++n) bfr[n] = *(const bf16x8*)&Bs[(wc + n * 16 + fr) * LDT + fg * 8];
#pragma unroll
    for (int m = 0; m < 4; ++m)
#pragma unroll
      for (int n = 0; n < 4; ++n)
        acc[m][n] = __builtin_amdgcn_mfma_f32_16x16x32_bf16(af[m], bfr[n], acc[m][n], 0, 0, 0);
    __syncthreads();
  }
#pragma unroll
  for (int m = 0; m < 4; ++m)
#pragma unroll
    for (int n = 0; n < 4; ++n)
#pragma unroll
      for (int j = 0; j < 4; ++j) {
        int r = bm + wr + m * 16 + fg * 4 + j;
        if (r < NN) C[(size_t)r * NC + wc + n * 16 + fr] = f2h_u(acc[m][n][j]);
      }
}

// ---------------- attention scores (fp16 H) ----------------
__global__ __launch_bounds__(256) void k_scores1(const ushort_t* __restrict__ Hh,
                                                 const float* __restrict__ att_s,
                                                 const float* __restrict__ att_d,
                                                 float4* __restrict__ as_out,
                                                 float4* __restrict__ ad_out) {
  int lane = threadIdx.x & 63;
  int n = blockIdx.x * 4 + (threadIdx.x >> 6);
  if (n >= NN) return;
  ushort4 hv = *(const ushort4*)&Hh[(size_t)n * DHID + lane * 4];
  float h0 = h2f_u(hv.x), h1 = h2f_u(hv.y), h2 = h2f_u(hv.z), h3 = h2f_u(hv.w);
  float4 sa = *(const float4*)&att_s[lane * 4];
  float4 da = *(const float4*)&att_d[lane * 4];
  float ps = h0 * sa.x + h1 * sa.y + h2 * sa.z + h3 * sa.w;
  float pd = h0 * da.x + h1 * da.y + h2 * da.z + h3 * da.w;
#pragma unroll
  for (int m = 1; m < 16; m <<= 1) { ps += __shfl_xor(ps, m); pd += __shfl_xor(pd, m); }
  float4 rs, rd;
  rs.x = __shfl(ps, 0);  rd.x = __shfl(pd, 0);
  rs.y = __shfl(ps, 16); rd.y = __shfl(pd, 16);
  rs.z = __shfl(ps, 32); rd.z = __shfl(pd, 32);
  rs.w = __shfl(ps, 48); rd.w = __shfl(pd, 48);
  if (lane == 0) { as_out[n] = rs; ad_out[n] = rd; }
}

__global__ __launch_bounds__(256) void k_scores2(const ushort_t* __restrict__ Hh,
                                                 const float* __restrict__ att_s,
                                                 const float* __restrict__ att_d,
                                                 float4* __restrict__ as_out,
                                                 float4* __restrict__ ad_out) {
  int lane = threadIdx.x & 63;
  int n = blockIdx.x * 4 + (threadIdx.x >> 6);
  if (n >= NN) return;
  ushort2 hv = *(const ushort2*)&Hh[(size_t)n * DOUT + lane * 2];
  float h0 = h2f_u(hv.x), h1 = h2f_u(hv.y);
  float2 sa = *(const float2*)&att_s[lane * 2];
  float2 da = *(const float2*)&att_d[lane * 2];
  float ps = h0 * sa.x + h1 * sa.y;
  float pd = h0 * da.x + h1 * da.y;
#pragma unroll
  for (int m = 1; m < 16; m <<= 1) { ps += __shfl_xor(ps, m); pd += __shfl_xor(pd, m); }
  float4 rs, rd;
  rs.x = __shfl(ps, 0);  rd.x = __shfl(pd, 0);
  rs.y = __shfl(ps, 16); rd.y = __shfl(pd, 16);
  rs.z = __shfl(ps, 32); rd.z = __shfl(pd, 32);
  rs.w = __shfl(ps, 48); rd.w = __shfl(pd, 48);
  if (lane == 0) { as_out[n] = rs; ad_out[n] = rd; }
}

// ---------------- GAT aggregation, layer 1 ----------------
// fast path: alphas finished in regs -> LDS table (s, 4 alphas per edge);
// pass C: direct LDS reads + 2-deep pipelined fp16 row gather + v_fma_mix.
__global__ __launch_bounds__(256) void k_agg1(const int* __restrict__ off, const int* __restrict__ csr,
                                              const float4* __restrict__ as_v, const float4* __restrict__ ad_v,
                                              const ushort_t* __restrict__ Hh, const float* __restrict__ bias,
                                              float* __restrict__ OUT) {
  __shared__ int s_tab[4][64];
  __shared__ float al_tab[4][256];
  int lane = threadIdx.x & 63;
  int wv = threadIdx.x >> 6;
  int n = blockIdx.x * 4 + wv;
  if (n >= NN) return;
  int beg = off[n], end = off[n + 1];
  int nt = end - beg;
  float4 adv = ad_v[n];
  float ad_[4] = {adv.x, adv.y, adv.z, adv.w};
  const int slot = lane >> 4, j = lane & 15;
  const int h = j >> 2;

  if (nt <= 64) {
    bool have = lane < nt;
    int s_l = csr[beg + (have ? lane : 0)];
    float4 a_l = as_v[s_l];
    float mx[4];
    mx[0] = have ? a_l.x : -INFINITY; mx[1] = have ? a_l.y : -INFINITY;
    mx[2] = have ? a_l.z : -INFINITY; mx[3] = have ? a_l.w : -INFINITY;
#pragma unroll
    for (int m = 1; m < 64; m <<= 1)
#pragma unroll
      for (int q = 0; q < 4; ++q) mx[q] = fmaxf(mx[q], __shfl_xor(mx[q], m));
    float emax[4];
#pragma unroll
    for (int q = 0; q < 4; ++q) emax[q] = lrelu(mx[q] + ad_[q]);
    float p0 = have ? __expf(lrelu(a_l.x + ad_[0]) - emax[0]) : 0.f;
    float p1 = have ? __expf(lrelu(a_l.y + ad_[1]) - emax[1]) : 0.f;
    float p2 = have ? __expf(lrelu(a_l.z + ad_[2]) - emax[2]) : 0.f;
    float p3 = have ? __expf(lrelu(a_l.w + ad_[3]) - emax[3]) : 0.f;
    float d0 = p0, d1 = p1, d2 = p2, d3 = p3;
#pragma unroll
    for (int m = 1; m < 64; m <<= 1) {
      d0 += __shfl_xor(d0, m); d1 += __shfl_xor(d1, m);
      d2 += __shfl_xor(d2, m); d3 += __shfl_xor(d3, m);
    }
    p0 *= 1.f / (d0 + 1e-16f); p1 *= 1.f / (d1 + 1e-16f);
    p2 *= 1.f / (d2 + 1e-16f); p3 *= 1.f / (d3 + 1e-16f);
    // publish per-edge (s, alpha[4]) to this wave's private LDS table
    s_tab[wv][lane] = s_l;
    *(float4*)&al_tab[wv][lane << 2] = make_float4(p0, p1, p2, p3);

    // pass C: 2-deep pipeline, 4 edge-slots x 16 lanes x 16 feats
    float acc[16] = {};
    int eA = slot;
    int sA = s_tab[wv][eA];
    float alA = (eA < nt) ? al_tab[wv][(eA << 2) | h] : 0.f;
    const f16x8* pA = (const f16x8*)&Hh[(size_t)sA * DHID + j * 16];
    f16x8 a0 = pA[0], a1 = pA[1];
    int eB = 4 + slot;
    int sB = s_tab[wv][eB & 63];
    float alB = (eB < nt) ? al_tab[wv][((eB & 63) << 2) | h] : 0.f;
    const f16x8* pB = (const f16x8*)&Hh[(size_t)sB * DHID + j * 16];
    f16x8 b0 = pB[0], b1 = pB[1];
    for (int eb = 0; eb < nt; eb += 4) {
      int eN = eb + 8 + slot;
      int sN = s_tab[wv][eN & 63];
      float alN = (eN < nt) ? al_tab[wv][((eN & 63) << 2) | h] : 0.f;
      const f16x8* pN = (const f16x8*)&Hh[(size_t)sN * DHID + j * 16];
      f16x8 n0 = pN[0], n1 = pN[1];
      fmah8(acc, alA, a0);
      fmah8(acc + 8, alA, a1);
      alA = alB; a0 = b0; a1 = b1;
      alB = alN; b0 = n0; b1 = n1;
    }
#pragma unroll
    for (int q = 0; q < 16; ++q) {
      acc[q] += __shfl_xor(acc[q], 16);
      acc[q] += __shfl_xor(acc[q], 32);
    }
    float o[4];
#pragma unroll
    for (int k = 0; k < 4; ++k) {
      float alo = (slot & 1) ? acc[4 + k] : acc[k];
      float ahi = (slot & 1) ? acc[12 + k] : acc[8 + k];
      o[k] = (slot & 2) ? ahi : alo;
    }
    float4 bv = *(const float4*)&bias[j * 16 + slot * 4];
    *(float4*)&OUT[(size_t)n * DHID + j * 16 + slot * 4] =
        make_float4(o[0] + bv.x, o[1] + bv.y, o[2] + bv.z, o[3] + bv.w);
    return;
  }

  // ---- slow path (deg > 64) ----
  float mx[4] = {-INFINITY, -INFINITY, -INFINITY, -INFINITY};
  for (int e = beg + lane; e < end; e += 64) {
    float4 a = as_v[csr[e]];
    mx[0] = fmaxf(mx[0], a.x); mx[1] = fmaxf(mx[1], a.y);
    mx[2] = fmaxf(mx[2], a.z); mx[3] = fmaxf(mx[3], a.w);
  }
#pragma unroll
  for (int m = 1; m < 64; m <<= 1)
#pragma unroll
    for (int q = 0; q < 4; ++q) mx[q] = fmaxf(mx[q], __shfl_xor(mx[q], m));
  float emax[4];
#pragma unroll
  for (int q = 0; q < 4; ++q) emax[q] = lrelu(mx[q] + ad_[q]);
  float den[4] = {0.f, 0.f, 0.f, 0.f};
  for (int e = beg + lane; e < end; e += 64) {
    float4 a = as_v[csr[e]];
    float aa[4] = {a.x, a.y, a.z, a.w};
#pragma unroll
    for (int q = 0; q < 4; ++q) den[q] += __expf(lrelu(aa[q] + ad_[q]) - emax[q]);
  }
#pragma unroll
  for (int m = 1; m < 64; m <<= 1)
#pragma unroll
    for (int q = 0; q < 4; ++q) den[q] += __shfl_xor(den[q], m);
  float adh = sel_h(h, ad_[0], ad_[1], ad_[2], ad_[3]);
  float emh = sel_h(h, emax[0], emax[1], emax[2], emax[3]);
  float dnh = sel_h(h, den[0], den[1], den[2], den[3]);
  float rdh = 1.f / (dnh + 1e-16f);
  float acc[16] = {};
  for (int eb = beg; eb < end; eb += 4) {
    int e = eb + slot;
    if (e < end) {
      int s = csr[e];
      float4 a = as_v[s];
      float ah = sel_h(h, a.x, a.y, a.z, a.w);
      float al = __expf(lrelu(ah + adh) - emh) * rdh;
      const f16x8* hr = (const f16x8*)&Hh[(size_t)s * DHID + j * 16];
      fmah8(acc, al, hr[0]);
      fmah8(acc + 8, al, hr[1]);
    }
  }
#pragma unroll
  for (int q = 0; q < 16; ++q) {
    acc[q] += __shfl_xor(acc[q], 16);
    acc[q] += __shfl_xor(acc[q], 32);
  }
  float o[4];
#pragma unroll
  for (int k = 0; k < 4; ++k) {
    float alo = (slot & 1) ? acc[4 + k] : acc[k];
    float ahi = (slot & 1) ? acc[12 + k] : acc[8 + k];
    o[k] = (slot & 2) ? ahi : alo;
  }
  float4 bv = *(const float4*)&bias[j * 16 + slot * 4];
  *(float4*)&OUT[(size_t)n * DHID + j * 16 + slot * 4] =
      make_float4(o[0] + bv.x, o[1] + bv.y, o[2] + bv.z, o[3] + bv.w);
}

// ---------------- GAT aggregation, layer 2 ----------------
__global__ __launch_bounds__(256) void k_agg2(const int* __restrict__ off, const int* __restrict__ csr,
                                              const float4* __restrict__ as_v, const float4* __restrict__ ad_v,
                                              const ushort_t* __restrict__ Hh, const float* __restrict__ bias,
                                              float* __restrict__ OUT) {
  __shared__ int s_tab[4][64];
  __shared__ float al_tab[4][256];
  int lane = threadIdx.x & 63;
  int wv = threadIdx.x >> 6;
  int n = blockIdx.x * 4 + wv;
  if (n >= NN) return;
  int beg = off[n], end = off[n + 1];
  int nt = end - beg;
  float4 adv = ad_v[n];
  float ad_[4] = {adv.x, adv.y, adv.z, adv.w};
  const int slot = lane >> 4, j = lane & 15;
  const int h = j >> 2;

  if (nt <= 64) {
    bool have = lane < nt;
    int s_l = csr[beg + (have ? lane : 0)];
    float4 a_l = as_v[s_l];
    float mx[4];
    mx[0] = have ? a_l.x : -INFINITY; mx[1] = have ? a_l.y : -INFINITY;
    mx[2] = have ? a_l.z : -INFINITY; mx[3] = have ? a_l.w : -INFINITY;
#pragma unroll
    for (int m = 1; m < 64; m <<= 1)
#pragma unroll
      for (int q = 0; q < 4; ++q) mx[q] = fmaxf(mx[q], __shfl_xor(mx[q], m));
    float emax[4];
#pragma unroll
    for (int q = 0; q < 4; ++q) emax[q] = lrelu(mx[q] + ad_[q]);
    float p0 = have ? __expf(lrelu(a_l.x + ad_[0]) - emax[0]) : 0.f;
    float p1 = have ? __expf(lrelu(a_l.y + ad_[1]) - emax[1]) : 0.f;
    float p2 = have ? __expf(lrelu(a_l.z + ad_[2]) - emax[2]) : 0.f;
    float p3 = have ? __expf(lrelu(a_l.w + ad_[3]) - emax[3]) : 0.f;
    float d0 = p0, d1 = p1, d2 = p2, d3 = p3;
#pragma unroll
    for (int m = 1; m < 64; m <<= 1) {
      d0 += __shfl_xor(d0, m); d1 += __shfl_xor(d1, m);
      d2 += __shfl_xor(d2, m); d3 += __shfl_xor(d3, m);
    }
    p0 *= 1.f / (d0 + 1e-16f); p1 *= 1.f / (d1 + 1e-16f);
    p2 *= 1.f / (d2 + 1e-16f); p3 *= 1.f / (d3 + 1e-16f);
    s_tab[wv][lane] = s_l;
    *(float4*)&al_tab[wv][lane << 2] = make_float4(p0, p1, p2, p3);

    float acc[8] = {};
    int eA = slot;
    int sA = s_tab[wv][eA];
    float alA = (eA < nt) ? al_tab[wv][(eA << 2) | h] : 0.f;
    f16x8 a0 = *(const f16x8*)&Hh[(size_t)sA * DOUT + j * 8];
    int eB = 4 + slot;
    int sB = s_tab[wv][eB & 63];
    float alB = (eB < nt) ? al_tab[wv][((eB & 63) << 2) | h] : 0.f;
    f16x8 b0 = *(const f16x8*)&Hh[(size_t)sB * DOUT + j * 8];
    for (int eb = 0; eb < nt; eb += 4) {
      int eN = eb + 8 + slot;
      int sN = s_tab[wv][eN & 63];
      float alN = (eN < nt) ? al_tab[wv][((eN & 63) << 2) | h] : 0.f;
      f16x8 n0 = *(const f16x8*)&Hh[(size_t)sN * DOUT + j * 8];
      fmah8(acc, alA, a0);
      alA = alB; a0 = b0;
      alB = alN; b0 = n0;
    }
#pragma unroll
    for (int q = 0; q < 8; ++q) {
      acc[q] += __shfl_xor(acc[q], 16);
      acc[q] += __shfl_xor(acc[q], 32);
    }
    float o0 = (slot & 2) ? ((slot & 1) ? acc[6] : acc[4]) : ((slot & 1) ? acc[2] : acc[0]);
    float o1 = (slot & 2) ? ((slot & 1) ? acc[7] : acc[5]) : ((slot & 1) ? acc[3] : acc[1]);
    float2 bv = *(const float2*)&bias[j * 8 + slot * 2];
    *(float2*)&OUT[(size_t)n * DOUT + j * 8 + slot * 2] = make_float2(o0 + bv.x, o1 + bv.y);
    return;
  }

  // slow path
  float mx[4] = {-INFINITY, -INFINITY, -INFINITY, -INFINITY};
  for (int e = beg + lane; e < end; e += 64) {
    float4 a = as_v[csr[e]];
    mx[0] = fmaxf(mx[0], a.x); mx[1] = fmaxf(mx[1], a.y);
    mx[2] = fmaxf(mx[2], a.z); mx[3] = fmaxf(mx[3], a.w);
  }
#pragma unroll
  for (int m = 1; m < 64; m <<= 1)
#pragma unroll
    for (int q = 0; q < 4; ++q) mx[q] = fmaxf(mx[q], __shfl_xor(mx[q], m));
  float emax[4];
#pragma unroll
  for (int q = 0; q < 4; ++q) emax[q] = lrelu(mx[q] + ad_[q]);
  float den[4] = {0.f, 0.f, 0.f, 0.f};
  for (int e = beg + lane; e < end; e += 64) {
    float4 a = as_v[csr[e]];
    float aa[4] = {a.x, a.y, a.z, a.w};
#pragma unroll
    for (int q = 0; q < 4; ++q) den[q] += __expf(lrelu(aa[q] + ad_[q]) - emax[q]);
  }
#pragma unroll
  for (int m = 1; m < 64; m <<= 1)
#pragma unroll
    for (int q = 0; q < 4; ++q) den[q] += __shfl_xor(den[q], m);
  float adh = sel_h(h, ad_[0], ad_[1], ad_[2], ad_[3]);
  float emh = sel_h(h, emax[0], emax[1], emax[2], emax[3]);
  float dnh = sel_h(h, den[0], den[1], den[2], den[3]);
  float rdh = 1.f / (dnh + 1e-16f);
  float acc[8] = {};
  for (int eb = beg; eb < end; eb += 4) {
    int e = eb + slot;
    if (e < end) {
      int s = csr[e];
      float4 a = as_v[s];
      float ah = sel_h(h, a.x, a.y, a.z, a.w);
      float al = __expf(lrelu(ah + adh) - emh) * rdh;
      f16x8 v0 = *(const f16x8*)&Hh[(size_t)s * DOUT + j * 8];
      fmah8(acc, al, v0);
    }
  }
#pragma unroll
  for (int q = 0; q < 8; ++q) {
    acc[q] += __shfl_xor(acc[q], 16);
    acc[q] += __shfl_xor(acc[q], 32);
  }
  float o0 = (slot & 2) ? ((slot & 1) ? acc[6] : acc[4]) : ((slot & 1) ? acc[2] : acc[0]);
  float o1 = (slot & 2) ? ((slot & 1) ? acc[7] : acc[5]) : ((slot & 1) ? acc[3] : acc[1]);
  float2 bv = *(const float2*)&bias[j * 8 + slot * 2];
  *(float2*)&OUT[(size_t)n * DOUT + j * 8 + slot * 2] = make_float2(o0 + bv.x, o1 + bv.y);
}

// ---------------- pooling ----------------
__global__ __launch_bounds__(256) void k_pool(const int* __restrict__ segstart,
                                              const float* __restrict__ OUT2,
                                              const float* __restrict__ OUT1,
                                              float* __restrict__ out) {
  int b = blockIdx.x;
  int t = threadIdx.x;
  int s = segstart[b], e = segstart[b + 1];
  float* ob = out + (size_t)b * 384;
  if (s >= e) {
    for (int i = t; i < 384; i += 256) ob[i] = 0.f;
    return;
  }
  if (t < 128) {
    float s0 = 0.f, s1 = 0.f;
    int n = s;
    for (; n + 1 < e; n += 2) {
      float v0 = OUT2[(size_t)n * DOUT + t];
      float v1 = OUT2[(size_t)(n + 1) * DOUT + t];
      s0 += fmaxf(v0, 0.f); s1 += fmaxf(v1, 0.f);
    }
    if (n < e) s0 += fmaxf(OUT2[(size_t)n * DOUT + t], 0.f);
    ob[t] = (s0 + s1) / (float)(e - s);
  } else {
    int k = t - 128;
    ob[128 + k] = OUT1[(size_t)s * DHID + k];
    ob[256 + k] = OUT1[(size_t)s * DHID + 128 + k];
  }
}

// ---------------- launch ----------------
extern "C" void kernel_launch(void* const* d_in, const int* in_sizes, int n_in,
                              void* d_out, int out_size, void* d_ws, size_t ws_size,
                              hipStream_t stream) {
  const float* x    = (const float*)d_in[0];
  const int*   ei   = (const int*)d_in[1];
  const int*   batch = (const int*)d_in[2];
  const float* W1   = (const float*)d_in[3];
  const float* as1w = (const float*)d_in[4];
  const float* ad1w = (const float*)d_in[5];
  const float* b1   = (const float*)d_in[6];
  const float* W2   = (const float*)d_in[7];
  const float* as2w = (const float*)d_in[8];
  const float* ad2w = (const float*)d_in[9];
  const float* b2   = (const float*)d_in[10];
  float* out = (float*)d_out;
  char* ws = (char*)d_ws;

  const int E = in_sizes[1] / 2;
  const int Etot = E + NN;

  // workspace layout (bytes)
  ushort_t* H1h = (ushort_t*)(ws + 0);        // NN*256*2 = 25.6 MB (dead after agg1)
  ushort_t* H2h = (ushort_t*)(ws + 0);        // NN*128*2 (aliases H1h)
  ushort_t* Wt2b = (ushort_t*)(ws + 13000000);// 262144 B (written after agg1)
  float*  OUT2 = (float*)(ws + 25600000);
  float*  OUT1 = (float*)(ws + 51200000);
  float4* as1  = (float4*)(ws + 102400000);
  float4* ad1  = (float4*)(ws + 103200000);
  float4* as2  = (float4*)(ws + 104000000);
  float4* ad2  = (float4*)(ws + 104800000);
  int* deg     = (int*)(ws + 105600000);
  int* cur     = (int*)(ws + 105800000);
  int* off     = (int*)(ws + 106000000);
  int* csr     = (int*)(ws + 106200016);
  int* segstart = (int*)(ws + 109600016);
  int* rootn   = (int*)(ws + 109602080);
  int* bsum    = (int*)(ws + 109802080);
  ushort_t* Wt1b = (ushort_t*)(ws + 105600000);

  const int TB = 256;
  const int NB_SCAN = (NN + 1023) / 1024;

  k_zero2<<<(NN + TB - 1) / TB, TB, 0, stream>>>(deg, cur, NN);
  k_hist<<<(Etot + TB - 1) / TB, TB, 0, stream>>>(ei, deg, E, Etot);
  k_scan1<<<NB_SCAN, 1024, 0, stream>>>(deg, off, bsum, NN);
  k_scan2<<<1, 64, 0, stream>>>(bsum, off, NB_SCAN, NN);
  k_scan3<<<NB_SCAN, 1024, 0, stream>>>(off, bsum, NN);
  k_scatter<<<(Etot + TB - 1) / TB, TB, 0, stream>>>(ei, off, cur, csr, E, Etot);
  k_segstart<<<(NBGRAPH + 1 + TB - 1) / TB, TB, 0, stream>>>(batch, segstart, NN, NBGRAPH);
  k_rootn<<<(NN + TB - 1) / TB, TB, 0, stream>>>(batch, segstart, rootn, NN);

  k_prepW<<<(DIN * DHID + TB - 1) / TB, TB, 0, stream>>>(W1, Wt1b, DIN, DHID);
  dim3 g1((NN + 127) / 128, DHID / 128);
  k_gemm1m<<<g1, TB, 0, stream>>>(x, Wt1b, H1h);
  k_scores1<<<(NN + 3) / 4, TB, 0, stream>>>(H1h, as1w, ad1w, as1, ad1);
  k_agg1<<<(NN + 3) / 4, TB, 0, stream>>>(off, csr, as1, ad1, H1h, b1, OUT1);

  k_prepW<<<((DHID + DIN) * DOUT + TB - 1) / TB, TB, 0, stream>>>(W2, Wt2b, DHID + DIN, DOUT);
  dim3 g2((NN + 127) / 128, 1);
  k_gemm2m<<<g2, TB, 0, stream>>>(OUT1, x, rootn, Wt2b, H2h);
  k_scores2<<<(NN + 3) / 4, TB, 0, stream>>>(H2h, as2w, ad2w, as2, ad2);
  k_agg2<<<(NN + 3) / 4, TB, 0, stream>>>(off, csr, as2, ad2, H2h, b2, OUT2);

  k_pool<<<NBGRAPH, TB, 0, stream>>>(segstart, OUT2, OUT1, out);
}

// Round 7
// 372.029 us; speedup vs baseline: 1.1893x; 1.1893x over previous
//
#include <hip/hip_runtime.h>

#define NN 50000
#define NBGRAPH 512
#define DIN 768
#define DHID 256
#define DOUT 128

typedef unsigned short ushort_t;
typedef __attribute__((ext_vector_type(8))) short bf16x8;
typedef __attribute__((ext_vector_type(4))) float f32x4;
typedef _Float16 f16_t;
typedef __attribute__((ext_vector_type(8))) _Float16 f16x8;

__device__ __forceinline__ float lrelu(float v) { return v > 0.f ? v : 0.2f * v; }

__device__ __forceinline__ ushort_t f2bf(float f) {
  unsigned int u = __builtin_bit_cast(unsigned int, f);
  u += 0x7fffu + ((u >> 16) & 1u);
  return (ushort_t)(u >> 16);
}
__device__ __forceinline__ float h2f_u(ushort_t u) { return (float)__builtin_bit_cast(f16_t, u); }
__device__ __forceinline__ ushort_t f2h_u(float f) { return __builtin_bit_cast(ushort_t, (f16_t)f); }

__device__ __forceinline__ float sel_h(int h, float q0, float q1, float q2, float q3) {
  float lo = (h & 1) ? q1 : q0;
  float hi = (h & 1) ? q3 : q2;
  return (h & 2) ? hi : lo;
}

// ---------------- CSR build ----------------
__global__ void k_zero2(int* __restrict__ a, int* __restrict__ b, int n) {
  int i = blockIdx.x * blockDim.x + threadIdx.x;
  if (i < n) { a[i] = 0; b[i] = 0; }
}

__global__ void k_hist(const int* __restrict__ ei, int* __restrict__ deg, int E, int Etot) {
  int e = blockIdx.x * blockDim.x + threadIdx.x;
  if (e >= Etot) return;
  int dst = (e < E) ? ei[e] : (e - E);
  atomicAdd(&deg[dst], 1);
}

__global__ __launch_bounds__(1024) void k_scan1(const int* __restrict__ deg, int* __restrict__ off,
                                                int* __restrict__ bsum, int n) {
  __shared__ int wsum[16];
  int tid = threadIdx.x, lane = tid & 63, w = tid >> 6;
  int i = blockIdx.x * 1024 + tid;
  int v = (i < n) ? deg[i] : 0;
  int x = v;
#pragma unroll
  for (int d = 1; d < 64; d <<= 1) { int t = __shfl_up(x, d); if (lane >= d) x += t; }
  if (lane == 63) wsum[w] = x;
  __syncthreads();
  if (tid < 16) {
    int y = wsum[tid];
#pragma unroll
    for (int d = 1; d < 16; d <<= 1) { int t = __shfl_up(y, d); if (tid >= d) y += t; }
    wsum[tid] = y;
  }
  __syncthreads();
  int base = (w > 0) ? wsum[w - 1] : 0;
  if (i < n) off[i] = base + x - v;
  if (tid == 1023) bsum[blockIdx.x] = wsum[15];
}

__global__ void k_scan2(int* __restrict__ bsum, int* __restrict__ off, int nb, int n) {
  int lane = threadIdx.x;
  int v = (lane < nb) ? bsum[lane] : 0;
  int x = v;
#pragma unroll
  for (int d = 1; d < 64; d <<= 1) { int t = __shfl_up(x, d); if (lane >= d) x += t; }
  if (lane < nb) bsum[lane] = x - v;
  if (lane == 63) off[n] = x;
}

__global__ void k_scan3(int* __restrict__ off, const int* __restrict__ bsum, int n) {
  int i = blockIdx.x * blockDim.x + threadIdx.x;
  if (i < n) off[i] += bsum[i >> 10];
}

__global__ void k_scatter(const int* __restrict__ ei, const int* __restrict__ off,
                          int* __restrict__ cur, int* __restrict__ csr, int E, int Etot) {
  int e = blockIdx.x * blockDim.x + threadIdx.x;
  if (e >= Etot) return;
  int dst, src;
  if (e < E) { dst = ei[e]; src = ei[E + e]; }
  else       { dst = src = e - E; }
  int p = atomicAdd(&cur[dst], 1);
  csr[off[dst] + p] = src;
}

// ---------------- roots / segments ----------------
__global__ void k_segstart(const int* __restrict__ batch, int* __restrict__ segstart, int n, int b_cnt) {
  int b = blockIdx.x * blockDim.x + threadIdx.x;
  if (b > b_cnt) return;
  int lo = 0, hi = n;
  while (lo < hi) { int mid = (lo + hi) >> 1; if (batch[mid] < b) lo = mid + 1; else hi = mid; }
  segstart[b] = lo;
}

__global__ void k_rootn(const int* __restrict__ batch, const int* __restrict__ segstart,
                        int* __restrict__ rootn, int n) {
  int i = blockIdx.x * blockDim.x + threadIdx.x;
  if (i < n) rootn[i] = segstart[batch[i]];
}

// ---------------- weight transpose+cast (bf16 for MFMA) ----------------
__global__ void k_prepW(const float* __restrict__ W, ushort_t* __restrict__ Wt, int K, int N) {
  int id = blockIdx.x * blockDim.x + threadIdx.x;
  if (id >= K * N) return;
  int n = id / K, k = id - n * K;
  Wt[(size_t)n * K + k] = f2bf(W[(size_t)k * N + n]);
}

// ---------------- MFMA GEMM1: H1h = fp16( bf16(x) @ bf16(W1) ) ----------------
#define LDT 40
__global__ __launch_bounds__(256) void k_gemm1m(const float* __restrict__ A,
                                                const ushort_t* __restrict__ Bt,
                                                ushort_t* __restrict__ C) {
  const int K = DIN, NC = DHID;
  __shared__ __align__(16) ushort_t As[128 * LDT];
  __shared__ __align__(16) ushort_t Bs[128 * LDT];
  const int tid = threadIdx.x;
  const int bm = blockIdx.x * 128;
  const int bn = blockIdx.y * 128;
  const int row = tid >> 1, half = tid & 1;
  const int arow = bm + row;
  const int wid = tid >> 6, lane = tid & 63;
  const int wr = (wid >> 1) * 64, wc = (wid & 1) * 64;
  const int fr = lane & 15, fg = lane >> 4;
  f32x4 acc[4][4] = {};

  for (int k0 = 0; k0 < K; k0 += 32) {
    {
      const int p = row * LDT + half * 16;
      if (arow < NN) {
        const float4* src = (const float4*)&A[(size_t)arow * K + k0 + half * 16];
#pragma unroll
        for (int i = 0; i < 4; ++i) {
          float4 v = src[i];
          ushort4 w;
          w.x = f2bf(v.x); w.y = f2bf(v.y); w.z = f2bf(v.z); w.w = f2bf(v.w);
          *(ushort4*)&As[p + i * 4] = w;
        }
      } else {
        ushort4 z = {0, 0, 0, 0};
#pragma unroll
        for (int i = 0; i < 4; ++i) *(ushort4*)&As[p + i * 4] = z;
      }
    }
#pragma unroll
    for (int i = 0; i < 2; ++i) {
      int c2 = tid + i * 256;
      int br = c2 >> 2, bq = c2 & 3;
      uint4 v = *(const uint4*)&Bt[(size_t)(bn + br) * K + k0 + bq * 8];
      *(uint4*)&Bs[br * LDT + bq * 8] = v;
    }
    __syncthreads();
    bf16x8 af[4], bfr[4];
#pragma unroll
    for (int m = 0; m < 4; ++m) af[m] = *(const bf16x8*)&As[(wr + m * 16 + fr) * LDT + fg * 8];
#pragma unroll
    for (int n = 0; n < 4; ++n) bfr[n] = *(const bf16x8*)&Bs[(wc + n * 16 + fr) * LDT + fg * 8];
#pragma unroll
    for (int m = 0; m < 4; ++m)
#pragma unroll
      for (int n = 0; n < 4; ++n)
        acc[m][n] = __builtin_amdgcn_mfma_f32_16x16x32_bf16(af[m], bfr[n], acc[m][n], 0, 0, 0);
    __syncthreads();
  }
#pragma unroll
  for (int m = 0; m < 4; ++m)
#pragma unroll
    for (int n = 0; n < 4; ++n)
#pragma unroll
      for (int j = 0; j < 4; ++j) {
        int r = bm + wr + m * 16 + fg * 4 + j;
        if (r < NN) C[(size_t)r * NC + bn + wc + n * 16 + fr] = f2h_u(acc[m][n][j]);
      }
}

// ---------------- MFMA GEMM2 ----------------
__global__ __launch_bounds__(256) void k_gemm2m(const float* __restrict__ OUT1,
                                                const float* __restrict__ X,
                                                const int* __restrict__ rootn,
                                                const ushort_t* __restrict__ Bt,
                                                ushort_t* __restrict__ C) {
  const int K = DHID + DIN, NC = DOUT;
  __shared__ __align__(16) ushort_t As[128 * LDT];
  __shared__ __align__(16) ushort_t Bs[128 * LDT];
  const int tid = threadIdx.x;
  const int bm = blockIdx.x * 128;
  const int row = tid >> 1, half = tid & 1;
  const int arow = bm + row;
  const int rn = (arow < NN) ? rootn[arow] : 0;
  const int wid = tid >> 6, lane = tid & 63;
  const int wr = (wid >> 1) * 64, wc = (wid & 1) * 64;
  const int fr = lane & 15, fg = lane >> 4;
  f32x4 acc[4][4] = {};

  for (int k0 = 0; k0 < K; k0 += 32) {
    {
      const int p = row * LDT + half * 16;
      const int kk = k0 + half * 16;
      if (arow < NN) {
        const float4* src = (kk < DHID)
            ? (const float4*)&OUT1[(size_t)arow * DHID + kk]
            : (const float4*)&X[(size_t)rn * DIN + (kk - DHID)];
#pragma unroll
        for (int i = 0; i < 4; ++i) {
          float4 v = src[i];
          ushort4 w;
          w.x = f2bf(fmaxf(v.x, 0.f)); w.y = f2bf(fmaxf(v.y, 0.f));
          w.z = f2bf(fmaxf(v.z, 0.f)); w.w = f2bf(fmaxf(v.w, 0.f));
          *(ushort4*)&As[p + i * 4] = w;
        }
      } else {
        ushort4 z = {0, 0, 0, 0};
#pragma unroll
        for (int i = 0; i < 4; ++i) *(ushort4*)&As[p + i * 4] = z;
      }
    }
#pragma unroll
    for (int i = 0; i < 2; ++i) {
      int c2 = tid + i * 256;
      int br = c2 >> 2, bq = c2 & 3;
      uint4 v = *(const uint4*)&Bt[(size_t)br * K + k0 + bq * 8];
      *(uint4*)&Bs[br * LDT + bq * 8] = v;
    }
    __syncthreads();
    bf16x8 af[4], bfr[4];
#pragma unroll
    for (int m = 0; m < 4; ++m) af[m] = *(const bf16x8*)&As[(wr + m * 16 + fr) * LDT + fg * 8];
#pragma unroll
    for (int n = 0; n < 4; ++n) bfr[n] = *(const bf16x8*)&Bs[(wc + n * 16 + fr) * LDT + fg * 8];
#pragma unroll
    for (int m = 0; m < 4; ++m)
#pragma unroll
      for (int n = 0; n < 4; ++n)
        acc[m][n] = __builtin_amdgcn_mfma_f32_16x16x32_bf16(af[m], bfr[n], acc[m][n], 0, 0, 0);
    __syncthreads();
  }
#pragma unroll
  for (int m = 0; m < 4; ++m)
#pragma unroll
    for (int n = 0; n < 4; ++n)
#pragma unroll
      for (int j = 0; j < 4; ++j) {
        int r = bm + wr + m * 16 + fg * 4 + j;
        if (r < NN) C[(size_t)r * NC + wc + n * 16 + fr] = f2h_u(acc[m][n][j]);
      }
}

// ---------------- attention scores (fp16 H) ----------------
__global__ __launch_bounds__(256) void k_scores1(const ushort_t* __restrict__ Hh,
                                                 const float* __restrict__ att_s,
                                                 const float* __restrict__ att_d,
                                                 float4* __restrict__ as_out,
                                                 float4* __restrict__ ad_out) {
  int lane = threadIdx.x & 63;
  int n = blockIdx.x * 4 + (threadIdx.x >> 6);
  if (n >= NN) return;
  ushort4 hv = *(const ushort4*)&Hh[(size_t)n * DHID + lane * 4];
  float h0 = h2f_u(hv.x), h1 = h2f_u(hv.y), h2 = h2f_u(hv.z), h3 = h2f_u(hv.w);
  float4 sa = *(const float4*)&att_s[lane * 4];
  float4 da = *(const float4*)&att_d[lane * 4];
  float ps = h0 * sa.x + h1 * sa.y + h2 * sa.z + h3 * sa.w;
  float pd = h0 * da.x + h1 * da.y + h2 * da.z + h3 * da.w;
#pragma unroll
  for (int m = 1; m < 16; m <<= 1) { ps += __shfl_xor(ps, m); pd += __shfl_xor(pd, m); }
  float4 rs, rd;
  rs.x = __shfl(ps, 0);  rd.x = __shfl(pd, 0);
  rs.y = __shfl(ps, 16); rd.y = __shfl(pd, 16);
  rs.z = __shfl(ps, 32); rd.z = __shfl(pd, 32);
  rs.w = __shfl(ps, 48); rd.w = __shfl(pd, 48);
  if (lane == 0) { as_out[n] = rs; ad_out[n] = rd; }
}

__global__ __launch_bounds__(256) void k_scores2(const ushort_t* __restrict__ Hh,
                                                 const float* __restrict__ att_s,
                                                 const float* __restrict__ att_d,
                                                 float4* __restrict__ as_out,
                                                 float4* __restrict__ ad_out) {
  int lane = threadIdx.x & 63;
  int n = blockIdx.x * 4 + (threadIdx.x >> 6);
  if (n >= NN) return;
  ushort2 hv = *(const ushort2*)&Hh[(size_t)n * DOUT + lane * 2];
  float h0 = h2f_u(hv.x), h1 = h2f_u(hv.y);
  float2 sa = *(const float2*)&att_s[lane * 2];
  float2 da = *(const float2*)&att_d[lane * 2];
  float ps = h0 * sa.x + h1 * sa.y;
  float pd = h0 * da.x + h1 * da.y;
#pragma unroll
  for (int m = 1; m < 16; m <<= 1) { ps += __shfl_xor(ps, m); pd += __shfl_xor(pd, m); }
  float4 rs, rd;
  rs.x = __shfl(ps, 0);  rd.x = __shfl(pd, 0);
  rs.y = __shfl(ps, 16); rd.y = __shfl(pd, 16);
  rs.z = __shfl(ps, 32); rd.z = __shfl(pd, 32);
  rs.w = __shfl(ps, 48); rd.w = __shfl(pd, 48);
  if (lane == 0) { as_out[n] = rs; ad_out[n] = rd; }
}

// ---------------- GAT aggregation, layer 1: one node per 16-lane group ----------------
// 16 nodes/block. Lane g of a group exclusively owns features [16g, 16g+16) -> head g>>2.
// Softmax: 16-lane shfl reductions; unnormalized alphas in padded LDS table.
__global__ __launch_bounds__(256) void k_agg1(const int* __restrict__ off, const int* __restrict__ csr,
                                              const float4* __restrict__ as_v, const float4* __restrict__ ad_v,
                                              const ushort_t* __restrict__ Hh, const float* __restrict__ bias,
                                              float* __restrict__ OUT) {
  __shared__ int s_tab[16][65];
  __shared__ __align__(16) float al_tab[16][260];   // [node][edge*4+head], padded stride
  const int tid = threadIdx.x;
  const int nd = tid >> 4;          // node-in-block 0..15
  const int g = tid & 15;           // lane-in-group
  const int hd = g >> 2;            // head of this lane's features
  const int n = blockIdx.x * 16 + nd;
  if (n >= NN) return;
  const int beg = off[n];
  const int nt = off[n + 1] - beg;
  const float4 adv = ad_v[n];

  float acc[16] = {};
  float rdh;

  if (nt <= 64) {
    // pass A: gather scores into LDS, track max (per-lane over its strided edges)
    float mx0 = -INFINITY, mx1 = -INFINITY, mx2 = -INFINITY, mx3 = -INFINITY;
    for (int le = g; le < nt; le += 16) {
      int s = csr[beg + le];
      float4 a = as_v[s];
      s_tab[nd][le] = s;
      *(float4*)&al_tab[nd][le << 2] = a;
      mx0 = fmaxf(mx0, a.x); mx1 = fmaxf(mx1, a.y);
      mx2 = fmaxf(mx2, a.z); mx3 = fmaxf(mx3, a.w);
    }
#pragma unroll
    for (int m = 1; m < 16; m <<= 1) {
      mx0 = fmaxf(mx0, __shfl_xor(mx0, m)); mx1 = fmaxf(mx1, __shfl_xor(mx1, m));
      mx2 = fmaxf(mx2, __shfl_xor(mx2, m)); mx3 = fmaxf(mx3, __shfl_xor(mx3, m));
    }
    float em0 = lrelu(mx0 + adv.x), em1 = lrelu(mx1 + adv.y);
    float em2 = lrelu(mx2 + adv.z), em3 = lrelu(mx3 + adv.w);
    // pass B: exp in place, accumulate sums
    float s0 = 0.f, s1 = 0.f, s2 = 0.f, s3 = 0.f;
    for (int le = g; le < nt; le += 16) {
      float4 a = *(const float4*)&al_tab[nd][le << 2];
      float p0 = __expf(lrelu(a.x + adv.x) - em0);
      float p1 = __expf(lrelu(a.y + adv.y) - em1);
      float p2 = __expf(lrelu(a.z + adv.z) - em2);
      float p3 = __expf(lrelu(a.w + adv.w) - em3);
      *(float4*)&al_tab[nd][le << 2] = make_float4(p0, p1, p2, p3);
      s0 += p0; s1 += p1; s2 += p2; s3 += p3;
    }
#pragma unroll
    for (int m = 1; m < 16; m <<= 1) {
      s0 += __shfl_xor(s0, m); s1 += __shfl_xor(s1, m);
      s2 += __shfl_xor(s2, m); s3 += __shfl_xor(s3, m);
    }
    float r0 = 1.f / (s0 + 1e-16f), r1 = 1.f / (s1 + 1e-16f);
    float r2 = 1.f / (s2 + 1e-16f), r3 = 1.f / (s3 + 1e-16f);
    rdh = sel_h(hd, r0, r1, r2, r3);

    // pass C: serial edges, 1-deep prefetch; lane owns 16 consecutive feats
    int sP = s_tab[nd][0];
    float pP = al_tab[nd][hd];
    f16x8 v0 = *(const f16x8*)&Hh[(size_t)sP * DHID + g * 16];
    f16x8 v1 = *(const f16x8*)&Hh[(size_t)sP * DHID + g * 16 + 8];
    for (int e = 0; e < nt; ++e) {
      int en = (e + 1 < nt) ? e + 1 : e;
      int sN = s_tab[nd][en];
      float pN = al_tab[nd][(en << 2) | hd];
      f16x8 n0 = *(const f16x8*)&Hh[(size_t)sN * DHID + g * 16];
      f16x8 n1 = *(const f16x8*)&Hh[(size_t)sN * DHID + g * 16 + 8];
      float al = pP * rdh;
#pragma unroll
      for (int q = 0; q < 8; ++q) acc[q] += al * (float)v0[q];
#pragma unroll
      for (int q = 0; q < 8; ++q) acc[8 + q] += al * (float)v1[q];
      pP = pN; v0 = n0; v1 = n1;
    }
  } else {
    // slow path (deg > 64): recompute alpha per edge
    float mx0 = -INFINITY, mx1 = -INFINITY, mx2 = -INFINITY, mx3 = -INFINITY;
    for (int le = g; le < nt; le += 16) {
      float4 a = as_v[csr[beg + le]];
      mx0 = fmaxf(mx0, a.x); mx1 = fmaxf(mx1, a.y);
      mx2 = fmaxf(mx2, a.z); mx3 = fmaxf(mx3, a.w);
    }
#pragma unroll
    for (int m = 1; m < 16; m <<= 1) {
      mx0 = fmaxf(mx0, __shfl_xor(mx0, m)); mx1 = fmaxf(mx1, __shfl_xor(mx1, m));
      mx2 = fmaxf(mx2, __shfl_xor(mx2, m)); mx3 = fmaxf(mx3, __shfl_xor(mx3, m));
    }
    float em0 = lrelu(mx0 + adv.x), em1 = lrelu(mx1 + adv.y);
    float em2 = lrelu(mx2 + adv.z), em3 = lrelu(mx3 + adv.w);
    float s0 = 0.f, s1 = 0.f, s2 = 0.f, s3 = 0.f;
    for (int le = g; le < nt; le += 16) {
      float4 a = as_v[csr[beg + le]];
      s0 += __expf(lrelu(a.x + adv.x) - em0);
      s1 += __expf(lrelu(a.y + adv.y) - em1);
      s2 += __expf(lrelu(a.z + adv.z) - em2);
      s3 += __expf(lrelu(a.w + adv.w) - em3);
    }
#pragma unroll
    for (int m = 1; m < 16; m <<= 1) {
      s0 += __shfl_xor(s0, m); s1 += __shfl_xor(s1, m);
      s2 += __shfl_xor(s2, m); s3 += __shfl_xor(s3, m);
    }
    rdh = sel_h(hd, 1.f / (s0 + 1e-16f), 1.f / (s1 + 1e-16f),
                    1.f / (s2 + 1e-16f), 1.f / (s3 + 1e-16f));
    float adh = sel_h(hd, adv.x, adv.y, adv.z, adv.w);
    float emh = sel_h(hd, em0, em1, em2, em3);
    for (int e = 0; e < nt; ++e) {
      int s = csr[beg + e];
      float4 a = as_v[s];
      float ah = sel_h(hd, a.x, a.y, a.z, a.w);
      float al = __expf(lrelu(ah + adh) - emh) * rdh;
      f16x8 v0 = *(const f16x8*)&Hh[(size_t)s * DHID + g * 16];
      f16x8 v1 = *(const f16x8*)&Hh[(size_t)s * DHID + g * 16 + 8];
#pragma unroll
      for (int q = 0; q < 8; ++q) acc[q] += al * (float)v0[q];
#pragma unroll
      for (int q = 0; q < 8; ++q) acc[8 + q] += al * (float)v1[q];
    }
  }

  // epilogue: lane owns feats [16g, 16g+16)
  const float* bv = &bias[g * 16];
  float* ob = &OUT[(size_t)n * DHID + g * 16];
#pragma unroll
  for (int k = 0; k < 4; ++k) {
    float4 b4 = *(const float4*)&bv[k * 4];
    *(float4*)&ob[k * 4] = make_float4(acc[k * 4] + b4.x, acc[k * 4 + 1] + b4.y,
                                       acc[k * 4 + 2] + b4.z, acc[k * 4 + 3] + b4.w);
  }
}

// ---------------- GAT aggregation, layer 2: one node per 16-lane group, D=128 ----------------
__global__ __launch_bounds__(256) void k_agg2(const int* __restrict__ off, const int* __restrict__ csr,
                                              const float4* __restrict__ as_v, const float4* __restrict__ ad_v,
                                              const ushort_t* __restrict__ Hh, const float* __restrict__ bias,
                                              float* __restrict__ OUT) {
  __shared__ int s_tab[16][65];
  __shared__ __align__(16) float al_tab[16][260];
  const int tid = threadIdx.x;
  const int nd = tid >> 4;
  const int g = tid & 15;
  const int hd = g >> 2;
  const int n = blockIdx.x * 16 + nd;
  if (n >= NN) return;
  const int beg = off[n];
  const int nt = off[n + 1] - beg;
  const float4 adv = ad_v[n];

  float acc[8] = {};
  float rdh;

  if (nt <= 64) {
    float mx0 = -INFINITY, mx1 = -INFINITY, mx2 = -INFINITY, mx3 = -INFINITY;
    for (int le = g; le < nt; le += 16) {
      int s = csr[beg + le];
      float4 a = as_v[s];
      s_tab[nd][le] = s;
      *(float4*)&al_tab[nd][le << 2] = a;
      mx0 = fmaxf(mx0, a.x); mx1 = fmaxf(mx1, a.y);
      mx2 = fmaxf(mx2, a.z); mx3 = fmaxf(mx3, a.w);
    }
#pragma unroll
    for (int m = 1; m < 16; m <<= 1) {
      mx0 = fmaxf(mx0, __shfl_xor(mx0, m)); mx1 = fmaxf(mx1, __shfl_xor(mx1, m));
      mx2 = fmaxf(mx2, __shfl_xor(mx2, m)); mx3 = fmaxf(mx3, __shfl_xor(mx3, m));
    }
    float em0 = lrelu(mx0 + adv.x), em1 = lrelu(mx1 + adv.y);
    float em2 = lrelu(mx2 + adv.z), em3 = lrelu(mx3 + adv.w);
    float s0 = 0.f, s1 = 0.f, s2 = 0.f, s3 = 0.f;
    for (int le = g; le < nt; le += 16) {
      float4 a = *(const float4*)&al_tab[nd][le << 2];
      float p0 = __expf(lrelu(a.x + adv.x) - em0);
      float p1 = __expf(lrelu(a.y + adv.y) - em1);
      float p2 = __expf(lrelu(a.z + adv.z) - em2);
      float p3 = __expf(lrelu(a.w + adv.w) - em3);
      *(float4*)&al_tab[nd][le << 2] = make_float4(p0, p1, p2, p3);
      s0 += p0; s1 += p1; s2 += p2; s3 += p3;
    }
#pragma unroll
    for (int m = 1; m < 16; m <<= 1) {
      s0 += __shfl_xor(s0, m); s1 += __shfl_xor(s1, m);
      s2 += __shfl_xor(s2, m); s3 += __shfl_xor(s3, m);
    }
    rdh = sel_h(hd, 1.f / (s0 + 1e-16f), 1.f / (s1 + 1e-16f),
                    1.f / (s2 + 1e-16f), 1.f / (s3 + 1e-16f));

    int sP = s_tab[nd][0];
    float pP = al_tab[nd][hd];
    f16x8 v0 = *(const f16x8*)&Hh[(size_t)sP * DOUT + g * 8];
    for (int e = 0; e < nt; ++e) {
      int en = (e + 1 < nt) ? e + 1 : e;
      int sN = s_tab[nd][en];
      float pN = al_tab[nd][(en << 2) | hd];
      f16x8 n0 = *(const f16x8*)&Hh[(size_t)sN * DOUT + g * 8];
      float al = pP * rdh;
#pragma unroll
      for (int q = 0; q < 8; ++q) acc[q] += al * (float)v0[q];
      pP = pN; v0 = n0;
    }
  } else {
    float mx0 = -INFINITY, mx1 = -INFINITY, mx2 = -INFINITY, mx3 = -INFINITY;
    for (int le = g; le < nt; le += 16) {
      float4 a = as_v[csr[beg + le]];
      mx0 = fmaxf(mx0, a.x); mx1 = fmaxf(mx1, a.y);
      mx2 = fmaxf(mx2, a.z); mx3 = fmaxf(mx3, a.w);
    }
#pragma unroll
    for (int m = 1; m < 16; m <<= 1) {
      mx0 = fmaxf(mx0, __shfl_xor(mx0, m)); mx1 = fmaxf(mx1, __shfl_xor(mx1, m));
      mx2 = fmaxf(mx2, __shfl_xor(mx2, m)); mx3 = fmaxf(mx3, __shfl_xor(mx3, m));
    }
    float em0 = lrelu(mx0 + adv.x), em1 = lrelu(mx1 + adv.y);
    float em2 = lrelu(mx2 + adv.z), em3 = lrelu(mx3 + adv.w);
    float s0 = 0.f, s1 = 0.f, s2 = 0.f, s3 = 0.f;
    for (int le = g; le < nt; le += 16) {
      float4 a = as_v[csr[beg + le]];
      s0 += __expf(lrelu(a.x + adv.x) - em0);
      s1 += __expf(lrelu(a.y + adv.y) - em1);
      s2 += __expf(lrelu(a.z + adv.z) - em2);
      s3 += __expf(lrelu(a.w + adv.w) - em3);
    }
#pragma unroll
    for (int m = 1; m < 16; m <<= 1) {
      s0 += __shfl_xor(s0, m); s1 += __shfl_xor(s1, m);
      s2 += __shfl_xor(s2, m); s3 += __shfl_xor(s3, m);
    }
    rdh = sel_h(hd, 1.f / (s0 + 1e-16f), 1.f / (s1 + 1e-16f),
                    1.f / (s2 + 1e-16f), 1.f / (s3 + 1e-16f));
    float adh = sel_h(hd, adv.x, adv.y, adv.z, adv.w);
    float emh = sel_h(hd, em0, em1, em2, em3);
    for (int e = 0; e < nt; ++e) {
      int s = csr[beg + e];
      float4 a = as_v[s];
      float ah = sel_h(hd, a.x, a.y, a.z, a.w);
      float al = __expf(lrelu(ah + adh) - emh) * rdh;
      f16x8 v0 = *(const f16x8*)&Hh[(size_t)s * DOUT + g * 8];
#pragma unroll
      for (int q = 0; q < 8; ++q) acc[q] += al * (float)v0[q];
    }
  }

  const float* bv = &bias[g * 8];
  float* ob = &OUT[(size_t)n * DOUT + g * 8];
#pragma unroll
  for (int k = 0; k < 2; ++k) {
    float4 b4 = *(const float4*)&bv[k * 4];
    *(float4*)&ob[k * 4] = make_float4(acc[k * 4] + b4.x, acc[k * 4 + 1] + b4.y,
                                       acc[k * 4 + 2] + b4.z, acc[k * 4 + 3] + b4.w);
  }
}

// ---------------- pooling ----------------
__global__ __launch_bounds__(256) void k_pool(const int* __restrict__ segstart,
                                              const float* __restrict__ OUT2,
                                              const float* __restrict__ OUT1,
                                              float* __restrict__ out) {
  int b = blockIdx.x;
  int t = threadIdx.x;
  int s = segstart[b], e = segstart[b + 1];
  float* ob = out + (size_t)b * 384;
  if (s >= e) {
    for (int i = t; i < 384; i += 256) ob[i] = 0.f;
    return;
  }
  if (t < 128) {
    float s0 = 0.f, s1 = 0.f;
    int n = s;
    for (; n + 1 < e; n += 2) {
      float v0 = OUT2[(size_t)n * DOUT + t];
      float v1 = OUT2[(size_t)(n + 1) * DOUT + t];
      s0 += fmaxf(v0, 0.f); s1 += fmaxf(v1, 0.f);
    }
    if (n < e) s0 += fmaxf(OUT2[(size_t)n * DOUT + t], 0.f);
    ob[t] = (s0 + s1) / (float)(e - s);
  } else {
    int k = t - 128;
    ob[128 + k] = OUT1[(size_t)s * DHID + k];
    ob[256 + k] = OUT1[(size_t)s * DHID + 128 + k];
  }
}

// ---------------- launch ----------------
extern "C" void kernel_launch(void* const* d_in, const int* in_sizes, int n_in,
                              void* d_out, int out_size, void* d_ws, size_t ws_size,
                              hipStream_t stream) {
  const float* x    = (const float*)d_in[0];
  const int*   ei   = (const int*)d_in[1];
  const int*   batch = (const int*)d_in[2];
  const float* W1   = (const float*)d_in[3];
  const float* as1w = (const float*)d_in[4];
  const float* ad1w = (const float*)d_in[5];
  const float* b1   = (const float*)d_in[6];
  const float* W2   = (const float*)d_in[7];
  const float* as2w = (const float*)d_in[8];
  const float* ad2w = (const float*)d_in[9];
  const float* b2   = (const float*)d_in[10];
  float* out = (float*)d_out;
  char* ws = (char*)d_ws;

  const int E = in_sizes[1] / 2;
  const int Etot = E + NN;

  // workspace layout (bytes)
  ushort_t* H1h = (ushort_t*)(ws + 0);        // NN*256*2 = 25.6 MB (dead after agg1)
  ushort_t* H2h = (ushort_t*)(ws + 0);        // NN*128*2 (aliases H1h)
  ushort_t* Wt2b = (ushort_t*)(ws + 13000000);// 262144 B (written after agg1)
  float*  OUT2 = (float*)(ws + 25600000);
  float*  OUT1 = (float*)(ws + 51200000);
  float4* as1  = (float4*)(ws + 102400000);
  float4* ad1  = (float4*)(ws + 103200000);
  float4* as2  = (float4*)(ws + 104000000);
  float4* ad2  = (float4*)(ws + 104800000);
  int* deg     = (int*)(ws + 105600000);
  int* cur     = (int*)(ws + 105800000);
  int* off     = (int*)(ws + 106000000);
  int* csr     = (int*)(ws + 106200016);
  int* segstart = (int*)(ws + 109600016);
  int* rootn   = (int*)(ws + 109602080);
  int* bsum    = (int*)(ws + 109802080);
  ushort_t* Wt1b = (ushort_t*)(ws + 105600000);

  const int TB = 256;
  const int NB_SCAN = (NN + 1023) / 1024;

  k_zero2<<<(NN + TB - 1) / TB, TB, 0, stream>>>(deg, cur, NN);
  k_hist<<<(Etot + TB - 1) / TB, TB, 0, stream>>>(ei, deg, E, Etot);
  k_scan1<<<NB_SCAN, 1024, 0, stream>>>(deg, off, bsum, NN);
  k_scan2<<<1, 64, 0, stream>>>(bsum, off, NB_SCAN, NN);
  k_scan3<<<NB_SCAN, 1024, 0, stream>>>(off, bsum, NN);
  k_scatter<<<(Etot + TB - 1) / TB, TB, 0, stream>>>(ei, off, cur, csr, E, Etot);
  k_segstart<<<(NBGRAPH + 1 + TB - 1) / TB, TB, 0, stream>>>(batch, segstart, NN, NBGRAPH);
  k_rootn<<<(NN + TB - 1) / TB, TB, 0, stream>>>(batch, segstart, rootn, NN);

  k_prepW<<<(DIN * DHID + TB - 1) / TB, TB, 0, stream>>>(W1, Wt1b, DIN, DHID);
  dim3 g1((NN + 127) / 128, DHID / 128);
  k_gemm1m<<<g1, TB, 0, stream>>>(x, Wt1b, H1h);
  k_scores1<<<(NN + 3) / 4, TB, 0, stream>>>(H1h, as1w, ad1w, as1, ad1);
  k_agg1<<<(NN + 15) / 16, TB, 0, stream>>>(off, csr, as1, ad1, H1h, b1, OUT1);

  k_prepW<<<((DHID + DIN) * DOUT + TB - 1) / TB, TB, 0, stream>>>(W2, Wt2b, DHID + DIN, DOUT);
  dim3 g2((NN + 127) / 128, 1);
  k_gemm2m<<<g2, TB, 0, stream>>>(OUT1, x, rootn, Wt2b, H2h);
  k_scores2<<<(NN + 3) / 4, TB, 0, stream>>>(H2h, as2w, ad2w, as2, ad2);
  k_agg2<<<(NN + 15) / 16, TB, 0, stream>>>(off, csr, as2, ad2, H2h, b2, OUT2);

  k_pool<<<NBGRAPH, TB, 0, stream>>>(segstart, OUT2, OUT1, out);
}

// Round 8
// 351.513 us; speedup vs baseline: 1.2588x; 1.0584x over previous
//
#include <hip/hip_runtime.h>

#define NN 50000
#define NBGRAPH 512
#define DIN 768
#define DHID 256
#define DOUT 128

typedef unsigned short ushort_t;
typedef __attribute__((ext_vector_type(8))) short bf16x8;
typedef __attribute__((ext_vector_type(4))) float f32x4;
typedef _Float16 f16_t;
typedef __attribute__((ext_vector_type(8))) _Float16 f16x8;

__device__ __forceinline__ float lrelu(float v) { return v > 0.f ? v : 0.2f * v; }

__device__ __forceinline__ ushort_t f2bf(float f) {
  unsigned int u = __builtin_bit_cast(unsigned int, f);
  u += 0x7fffu + ((u >> 16) & 1u);
  return (ushort_t)(u >> 16);
}
__device__ __forceinline__ float h2f_u(ushort_t u) { return (float)__builtin_bit_cast(f16_t, u); }
__device__ __forceinline__ ushort_t f2h_u(float f) { return __builtin_bit_cast(ushort_t, (f16_t)f); }

__device__ __forceinline__ float sel_h(int h, float q0, float q1, float q2, float q3) {
  float lo = (h & 1) ? q1 : q0;
  float hi = (h & 1) ? q3 : q2;
  return (h & 2) ? hi : lo;
}

// ---------------- CSR build ----------------
__global__ void k_zero2(int* __restrict__ a, int* __restrict__ b, int n) {
  int i = blockIdx.x * blockDim.x + threadIdx.x;
  if (i < n) { a[i] = 0; b[i] = 0; }
}

__global__ void k_hist(const int* __restrict__ ei, int* __restrict__ deg, int E, int Etot) {
  int e = blockIdx.x * blockDim.x + threadIdx.x;
  if (e >= Etot) return;
  int dst = (e < E) ? ei[e] : (e - E);
  atomicAdd(&deg[dst], 1);
}

__global__ __launch_bounds__(1024) void k_scan1(const int* __restrict__ deg, int* __restrict__ off,
                                                int* __restrict__ bsum, int n) {
  __shared__ int wsum[16];
  int tid = threadIdx.x, lane = tid & 63, w = tid >> 6;
  int i = blockIdx.x * 1024 + tid;
  int v = (i < n) ? deg[i] : 0;
  int x = v;
#pragma unroll
  for (int d = 1; d < 64; d <<= 1) { int t = __shfl_up(x, d); if (lane >= d) x += t; }
  if (lane == 63) wsum[w] = x;
  __syncthreads();
  if (tid < 16) {
    int y = wsum[tid];
#pragma unroll
    for (int d = 1; d < 16; d <<= 1) { int t = __shfl_up(y, d); if (tid >= d) y += t; }
    wsum[tid] = y;
  }
  __syncthreads();
  int base = (w > 0) ? wsum[w - 1] : 0;
  if (i < n) off[i] = base + x - v;
  if (tid == 1023) bsum[blockIdx.x] = wsum[15];
}

__global__ void k_scan2(int* __restrict__ bsum, int* __restrict__ off, int nb, int n) {
  int lane = threadIdx.x;
  int v = (lane < nb) ? bsum[lane] : 0;
  int x = v;
#pragma unroll
  for (int d = 1; d < 64; d <<= 1) { int t = __shfl_up(x, d); if (lane >= d) x += t; }
  if (lane < nb) bsum[lane] = x - v;
  if (lane == 63) off[n] = x;
}

__global__ void k_scan3(int* __restrict__ off, const int* __restrict__ bsum, int n) {
  int i = blockIdx.x * blockDim.x + threadIdx.x;
  if (i < n) off[i] += bsum[i >> 10];
}

__global__ void k_scatter(const int* __restrict__ ei, const int* __restrict__ off,
                          int* __restrict__ cur, int* __restrict__ csr, int E, int Etot) {
  int e = blockIdx.x * blockDim.x + threadIdx.x;
  if (e >= Etot) return;
  int dst, src;
  if (e < E) { dst = ei[e]; src = ei[E + e]; }
  else       { dst = src = e - E; }
  int p = atomicAdd(&cur[dst], 1);
  csr[off[dst] + p] = src;
}

// ---------------- roots / segments ----------------
__global__ void k_segstart(const int* __restrict__ batch, int* __restrict__ segstart, int n, int b_cnt) {
  int b = blockIdx.x * blockDim.x + threadIdx.x;
  if (b > b_cnt) return;
  int lo = 0, hi = n;
  while (lo < hi) { int mid = (lo + hi) >> 1; if (batch[mid] < b) lo = mid + 1; else hi = mid; }
  segstart[b] = lo;
}

__global__ void k_rootn(const int* __restrict__ batch, const int* __restrict__ segstart,
                        int* __restrict__ rootn, int n) {
  int i = blockIdx.x * blockDim.x + threadIdx.x;
  if (i < n) rootn[i] = segstart[batch[i]];
}

// ---------------- weight transpose+cast (bf16 for MFMA) ----------------
__global__ void k_prepW(const float* __restrict__ W, ushort_t* __restrict__ Wt, int K, int N) {
  int id = blockIdx.x * blockDim.x + threadIdx.x;
  if (id >= K * N) return;
  int n = id / K, k = id - n * K;
  Wt[(size_t)n * K + k] = f2bf(W[(size_t)k * N + n]);
}

// ---------------- MFMA GEMM1: H1h = fp16( bf16(x) @ bf16(W1) ), reg-prefetch pipelined ----------------
#define LDT 40
__global__ __launch_bounds__(256) void k_gemm1m(const float* __restrict__ A,
                                                const ushort_t* __restrict__ Bt,
                                                ushort_t* __restrict__ C) {
  const int K = DIN, NC = DHID;
  __shared__ __align__(16) ushort_t As[128 * LDT];
  __shared__ __align__(16) ushort_t Bs[128 * LDT];
  const int tid = threadIdx.x;
  const int bm = blockIdx.x * 128;
  const int bn = blockIdx.y * 128;
  const int row = tid >> 1, half = tid & 1;
  const int arow = bm + row;
  const bool rok = arow < NN;
  const int wid = tid >> 6, lane = tid & 63;
  const int wr = (wid >> 1) * 64, wc = (wid & 1) * 64;
  const int fr = lane & 15, fg = lane >> 4;
  const float* aptr = &A[(size_t)(rok ? arow : 0) * K + half * 16];
  const ushort_t* bptr0 = &Bt[(size_t)(bn + (tid >> 2)) * K + (tid & 3) * 8];
  const ushort_t* bptr1 = &Bt[(size_t)(bn + ((tid + 256) >> 2)) * K + ((tid + 256) & 3) * 8];
  f32x4 acc[4][4] = {};

  float4 pa0, pa1, pa2, pa3;
  uint4 pb0, pb1;
  // prologue: k0 = 0
  {
    const float4* s = (const float4*)aptr;
    pa0 = s[0]; pa1 = s[1]; pa2 = s[2]; pa3 = s[3];
    pb0 = *(const uint4*)bptr0;
    pb1 = *(const uint4*)bptr1;
  }

  for (int k0 = 0; k0 < K; k0 += 32) {
    // stage current regs -> LDS
    {
      const int p = row * LDT + half * 16;
      ushort4 w0, w1, w2, w3;
      if (rok) {
        w0.x = f2bf(pa0.x); w0.y = f2bf(pa0.y); w0.z = f2bf(pa0.z); w0.w = f2bf(pa0.w);
        w1.x = f2bf(pa1.x); w1.y = f2bf(pa1.y); w1.z = f2bf(pa1.z); w1.w = f2bf(pa1.w);
        w2.x = f2bf(pa2.x); w2.y = f2bf(pa2.y); w2.z = f2bf(pa2.z); w2.w = f2bf(pa2.w);
        w3.x = f2bf(pa3.x); w3.y = f2bf(pa3.y); w3.z = f2bf(pa3.z); w3.w = f2bf(pa3.w);
      } else {
        w0 = w1 = w2 = w3 = make_ushort4(0, 0, 0, 0);
      }
      *(ushort4*)&As[p + 0] = w0; *(ushort4*)&As[p + 4] = w1;
      *(ushort4*)&As[p + 8] = w2; *(ushort4*)&As[p + 12] = w3;
      *(uint4*)&Bs[(tid >> 2) * LDT + (tid & 3) * 8] = pb0;
      *(uint4*)&Bs[((tid + 256) >> 2) * LDT + ((tid + 256) & 3) * 8] = pb1;
    }
    __syncthreads();
    // issue next tile's global loads (latency hidden under MFMA below)
    const bool more = (k0 + 32) < K;
    float4 na0, na1, na2, na3;
    uint4 nb0, nb1;
    if (more) {
      const float4* s = (const float4*)(aptr + k0 + 32);
      na0 = s[0]; na1 = s[1]; na2 = s[2]; na3 = s[3];
      nb0 = *(const uint4*)(bptr0 + k0 + 32);
      nb1 = *(const uint4*)(bptr1 + k0 + 32);
    }
    // compute
    bf16x8 af[4], bfr[4];
#pragma unroll
    for (int m = 0; m < 4; ++m) af[m] = *(const bf16x8*)&As[(wr + m * 16 + fr) * LDT + fg * 8];
#pragma unroll
    for (int n = 0; n < 4; ++n) bfr[n] = *(const bf16x8*)&Bs[(wc + n * 16 + fr) * LDT + fg * 8];
#pragma unroll
    for (int m = 0; m < 4; ++m)
#pragma unroll
      for (int n = 0; n < 4; ++n)
        acc[m][n] = __builtin_amdgcn_mfma_f32_16x16x32_bf16(af[m], bfr[n], acc[m][n], 0, 0, 0);
    __syncthreads();
    if (more) {
      pa0 = na0; pa1 = na1; pa2 = na2; pa3 = na3;
      pb0 = nb0; pb1 = nb1;
    }
  }
#pragma unroll
  for (int m = 0; m < 4; ++m)
#pragma unroll
    for (int n = 0; n < 4; ++n)
#pragma unroll
      for (int j = 0; j < 4; ++j) {
        int r = bm + wr + m * 16 + fg * 4 + j;
        if (r < NN) C[(size_t)r * NC + bn + wc + n * 16 + fr] = f2h_u(acc[m][n][j]);
      }
}

// ---------------- MFMA GEMM2: H2h = fp16( bf16(relu(concat(OUT1, x[root]))) @ bf16(W2) ) ----------------
__global__ __launch_bounds__(256) void k_gemm2m(const float* __restrict__ OUT1,
                                                const float* __restrict__ X,
                                                const int* __restrict__ rootn,
                                                const ushort_t* __restrict__ Bt,
                                                ushort_t* __restrict__ C) {
  const int K = DHID + DIN, NC = DOUT;
  __shared__ __align__(16) ushort_t As[128 * LDT];
  __shared__ __align__(16) ushort_t Bs[128 * LDT];
  const int tid = threadIdx.x;
  const int bm = blockIdx.x * 128;
  const int row = tid >> 1, half = tid & 1;
  const int arow = bm + row;
  const bool rok = arow < NN;
  const int rn = rok ? rootn[arow] : 0;
  const int wid = tid >> 6, lane = tid & 63;
  const int wr = (wid >> 1) * 64, wc = (wid & 1) * 64;
  const int fr = lane & 15, fg = lane >> 4;
  const float* o1ptr = &OUT1[(size_t)(rok ? arow : 0) * DHID + half * 16];
  const float* xptr = &X[(size_t)rn * DIN + half * 16];
  const ushort_t* bptr0 = &Bt[(size_t)(tid >> 2) * K + (tid & 3) * 8];
  const ushort_t* bptr1 = &Bt[(size_t)((tid + 256) >> 2) * K + ((tid + 256) & 3) * 8];
  f32x4 acc[4][4] = {};

  float4 pa0, pa1, pa2, pa3;
  uint4 pb0, pb1;
  {
    const float4* s = (const float4*)o1ptr;   // k0=0 is always in OUT1 region
    pa0 = s[0]; pa1 = s[1]; pa2 = s[2]; pa3 = s[3];
    pb0 = *(const uint4*)bptr0;
    pb1 = *(const uint4*)bptr1;
  }

  for (int k0 = 0; k0 < K; k0 += 32) {
    {
      const int p = row * LDT + half * 16;
      ushort4 w0, w1, w2, w3;
      if (rok) {
        w0.x = f2bf(fmaxf(pa0.x, 0.f)); w0.y = f2bf(fmaxf(pa0.y, 0.f));
        w0.z = f2bf(fmaxf(pa0.z, 0.f)); w0.w = f2bf(fmaxf(pa0.w, 0.f));
        w1.x = f2bf(fmaxf(pa1.x, 0.f)); w1.y = f2bf(fmaxf(pa1.y, 0.f));
        w1.z = f2bf(fmaxf(pa1.z, 0.f)); w1.w = f2bf(fmaxf(pa1.w, 0.f));
        w2.x = f2bf(fmaxf(pa2.x, 0.f)); w2.y = f2bf(fmaxf(pa2.y, 0.f));
        w2.z = f2bf(fmaxf(pa2.z, 0.f)); w2.w = f2bf(fmaxf(pa2.w, 0.f));
        w3.x = f2bf(fmaxf(pa3.x, 0.f)); w3.y = f2bf(fmaxf(pa3.y, 0.f));
        w3.z = f2bf(fmaxf(pa3.z, 0.f)); w3.w = f2bf(fmaxf(pa3.w, 0.f));
      } else {
        w0 = w1 = w2 = w3 = make_ushort4(0, 0, 0, 0);
      }
      *(ushort4*)&As[p + 0] = w0; *(ushort4*)&As[p + 4] = w1;
      *(ushort4*)&As[p + 8] = w2; *(ushort4*)&As[p + 12] = w3;
      *(uint4*)&Bs[(tid >> 2) * LDT + (tid & 3) * 8] = pb0;
      *(uint4*)&Bs[((tid + 256) >> 2) * LDT + ((tid + 256) & 3) * 8] = pb1;
    }
    __syncthreads();
    const bool more = (k0 + 32) < K;
    float4 na0, na1, na2, na3;
    uint4 nb0, nb1;
    if (more) {
      const int kk = k0 + 32 + half * 16;   // this chunk's k-origin
      const float4* s = (kk < DHID) ? (const float4*)(o1ptr + k0 + 32)
                                    : (const float4*)(xptr + (k0 + 32 - DHID));
      na0 = s[0]; na1 = s[1]; na2 = s[2]; na3 = s[3];
      nb0 = *(const uint4*)(bptr0 + k0 + 32);
      nb1 = *(const uint4*)(bptr1 + k0 + 32);
    }
    bf16x8 af[4], bfr[4];
#pragma unroll
    for (int m = 0; m < 4; ++m) af[m] = *(const bf16x8*)&As[(wr + m * 16 + fr) * LDT + fg * 8];
#pragma unroll
    for (int n = 0; n < 4; ++n) bfr[n] = *(const bf16x8*)&Bs[(wc + n * 16 + fr) * LDT + fg * 8];
#pragma unroll
    for (int m = 0; m < 4; ++m)
#pragma unroll
      for (int n = 0; n < 4; ++n)
        acc[m][n] = __builtin_amdgcn_mfma_f32_16x16x32_bf16(af[m], bfr[n], acc[m][n], 0, 0, 0);
    __syncthreads();
    if (more) {
      pa0 = na0; pa1 = na1; pa2 = na2; pa3 = na3;
      pb0 = nb0; pb1 = nb1;
    }
  }
#pragma unroll
  for (int m = 0; m < 4; ++m)
#pragma unroll
    for (int n = 0; n < 4; ++n)
#pragma unroll
      for (int j = 0; j < 4; ++j) {
        int r = bm + wr + m * 16 + fg * 4 + j;
        if (r < NN) C[(size_t)r * NC + wc + n * 16 + fr] = f2h_u(acc[m][n][j]);
      }
}

// ---------------- attention scores (fp16 H) ----------------
__global__ __launch_bounds__(256) void k_scores1(const ushort_t* __restrict__ Hh,
                                                 const float* __restrict__ att_s,
                                                 const float* __restrict__ att_d,
                                                 float4* __restrict__ as_out,
                                                 float4* __restrict__ ad_out) {
  int lane = threadIdx.x & 63;
  int n = blockIdx.x * 4 + (threadIdx.x >> 6);
  if (n >= NN) return;
  ushort4 hv = *(const ushort4*)&Hh[(size_t)n * DHID + lane * 4];
  float h0 = h2f_u(hv.x), h1 = h2f_u(hv.y), h2 = h2f_u(hv.z), h3 = h2f_u(hv.w);
  float4 sa = *(const float4*)&att_s[lane * 4];
  float4 da = *(const float4*)&att_d[lane * 4];
  float ps = h0 * sa.x + h1 * sa.y + h2 * sa.z + h3 * sa.w;
  float pd = h0 * da.x + h1 * da.y + h2 * da.z + h3 * da.w;
#pragma unroll
  for (int m = 1; m < 16; m <<= 1) { ps += __shfl_xor(ps, m); pd += __shfl_xor(pd, m); }
  float4 rs, rd;
  rs.x = __shfl(ps, 0);  rd.x = __shfl(pd, 0);
  rs.y = __shfl(ps, 16); rd.y = __shfl(pd, 16);
  rs.z = __shfl(ps, 32); rd.z = __shfl(pd, 32);
  rs.w = __shfl(ps, 48); rd.w = __shfl(pd, 48);
  if (lane == 0) { as_out[n] = rs; ad_out[n] = rd; }
}

__global__ __launch_bounds__(256) void k_scores2(const ushort_t* __restrict__ Hh,
                                                 const float* __restrict__ att_s,
                                                 const float* __restrict__ att_d,
                                                 float4* __restrict__ as_out,
                                                 float4* __restrict__ ad_out) {
  int lane = threadIdx.x & 63;
  int n = blockIdx.x * 4 + (threadIdx.x >> 6);
  if (n >= NN) return;
  ushort2 hv = *(const ushort2*)&Hh[(size_t)n * DOUT + lane * 2];
  float h0 = h2f_u(hv.x), h1 = h2f_u(hv.y);
  float2 sa = *(const float2*)&att_s[lane * 2];
  float2 da = *(const float2*)&att_d[lane * 2];
  float ps = h0 * sa.x + h1 * sa.y;
  float pd = h0 * da.x + h1 * da.y;
#pragma unroll
  for (int m = 1; m < 16; m <<= 1) { ps += __shfl_xor(ps, m); pd += __shfl_xor(pd, m); }
  float4 rs, rd;
  rs.x = __shfl(ps, 0);  rd.x = __shfl(pd, 0);
  rs.y = __shfl(ps, 16); rd.y = __shfl(pd, 16);
  rs.z = __shfl(ps, 32); rd.z = __shfl(pd, 32);
  rs.w = __shfl(ps, 48); rd.w = __shfl(pd, 48);
  if (lane == 0) { as_out[n] = rs; ad_out[n] = rd; }
}

// ---------------- GAT aggregation, layer 1: one node per 16-lane group ----------------
__global__ __launch_bounds__(256) void k_agg1(const int* __restrict__ off, const int* __restrict__ csr,
                                              const float4* __restrict__ as_v, const float4* __restrict__ ad_v,
                                              const ushort_t* __restrict__ Hh, const float* __restrict__ bias,
                                              float* __restrict__ OUT) {
  __shared__ int s_tab[16][65];
  __shared__ __align__(16) float al_tab[16][260];
  const int tid = threadIdx.x;
  const int nd = tid >> 4;
  const int g = tid & 15;
  const int hd = g >> 2;
  const int n = blockIdx.x * 16 + nd;
  if (n >= NN) return;
  const int beg = off[n];
  const int nt = off[n + 1] - beg;
  const float4 adv = ad_v[n];

  float acc[16] = {};
  float rdh;

  if (nt <= 64) {
    float mx0 = -INFINITY, mx1 = -INFINITY, mx2 = -INFINITY, mx3 = -INFINITY;
    for (int le = g; le < nt; le += 16) {
      int s = csr[beg + le];
      float4 a = as_v[s];
      s_tab[nd][le] = s;
      *(float4*)&al_tab[nd][le << 2] = a;
      mx0 = fmaxf(mx0, a.x); mx1 = fmaxf(mx1, a.y);
      mx2 = fmaxf(mx2, a.z); mx3 = fmaxf(mx3, a.w);
    }
#pragma unroll
    for (int m = 1; m < 16; m <<= 1) {
      mx0 = fmaxf(mx0, __shfl_xor(mx0, m)); mx1 = fmaxf(mx1, __shfl_xor(mx1, m));
      mx2 = fmaxf(mx2, __shfl_xor(mx2, m)); mx3 = fmaxf(mx3, __shfl_xor(mx3, m));
    }
    float em0 = lrelu(mx0 + adv.x), em1 = lrelu(mx1 + adv.y);
    float em2 = lrelu(mx2 + adv.z), em3 = lrelu(mx3 + adv.w);
    float s0 = 0.f, s1 = 0.f, s2 = 0.f, s3 = 0.f;
    for (int le = g; le < nt; le += 16) {
      float4 a = *(const float4*)&al_tab[nd][le << 2];
      float p0 = __expf(lrelu(a.x + adv.x) - em0);
      float p1 = __expf(lrelu(a.y + adv.y) - em1);
      float p2 = __expf(lrelu(a.z + adv.z) - em2);
      float p3 = __expf(lrelu(a.w + adv.w) - em3);
      *(float4*)&al_tab[nd][le << 2] = make_float4(p0, p1, p2, p3);
      s0 += p0; s1 += p1; s2 += p2; s3 += p3;
    }
#pragma unroll
    for (int m = 1; m < 16; m <<= 1) {
      s0 += __shfl_xor(s0, m); s1 += __shfl_xor(s1, m);
      s2 += __shfl_xor(s2, m); s3 += __shfl_xor(s3, m);
    }
    rdh = sel_h(hd, 1.f / (s0 + 1e-16f), 1.f / (s1 + 1e-16f),
                    1.f / (s2 + 1e-16f), 1.f / (s3 + 1e-16f));

    int sP = s_tab[nd][0];
    float pP = al_tab[nd][hd];
    f16x8 v0 = *(const f16x8*)&Hh[(size_t)sP * DHID + g * 16];
    f16x8 v1 = *(const f16x8*)&Hh[(size_t)sP * DHID + g * 16 + 8];
    for (int e = 0; e < nt; ++e) {
      int en = (e + 1 < nt) ? e + 1 : e;
      int sN = s_tab[nd][en];
      float pN = al_tab[nd][(en << 2) | hd];
      f16x8 n0 = *(const f16x8*)&Hh[(size_t)sN * DHID + g * 16];
      f16x8 n1 = *(const f16x8*)&Hh[(size_t)sN * DHID + g * 16 + 8];
      float al = pP * rdh;
#pragma unroll
      for (int q = 0; q < 8; ++q) acc[q] += al * (float)v0[q];
#pragma unroll
      for (int q = 0; q < 8; ++q) acc[8 + q] += al * (float)v1[q];
      pP = pN; v0 = n0; v1 = n1;
    }
  } else {
    float mx0 = -INFINITY, mx1 = -INFINITY, mx2 = -INFINITY, mx3 = -INFINITY;
    for (int le = g; le < nt; le += 16) {
      float4 a = as_v[csr[beg + le]];
      mx0 = fmaxf(mx0, a.x); mx1 = fmaxf(mx1, a.y);
      mx2 = fmaxf(mx2, a.z); mx3 = fmaxf(mx3, a.w);
    }
#pragma unroll
    for (int m = 1; m < 16; m <<= 1) {
      mx0 = fmaxf(mx0, __shfl_xor(mx0, m)); mx1 = fmaxf(mx1, __shfl_xor(mx1, m));
      mx2 = fmaxf(mx2, __shfl_xor(mx2, m)); mx3 = fmaxf(mx3, __shfl_xor(mx3, m));
    }
    float em0 = lrelu(mx0 + adv.x), em1 = lrelu(mx1 + adv.y);
    float em2 = lrelu(mx2 + adv.z), em3 = lrelu(mx3 + adv.w);
    float s0 = 0.f, s1 = 0.f, s2 = 0.f, s3 = 0.f;
    for (int le = g; le < nt; le += 16) {
      float4 a = as_v[csr[beg + le]];
      s0 += __expf(lrelu(a.x + adv.x) - em0);
      s1 += __expf(lrelu(a.y + adv.y) - em1);
      s2 += __expf(lrelu(a.z + adv.z) - em2);
      s3 += __expf(lrelu(a.w + adv.w) - em3);
    }
#pragma unroll
    for (int m = 1; m < 16; m <<= 1) {
      s0 += __shfl_xor(s0, m); s1 += __shfl_xor(s1, m);
      s2 += __shfl_xor(s2, m); s3 += __shfl_xor(s3, m);
    }
    rdh = sel_h(hd, 1.f / (s0 + 1e-16f), 1.f / (s1 + 1e-16f),
                    1.f / (s2 + 1e-16f), 1.f / (s3 + 1e-16f));
    float adh = sel_h(hd, adv.x, adv.y, adv.z, adv.w);
    float emh = sel_h(hd, em0, em1, em2, em3);
    for (int e = 0; e < nt; ++e) {
      int s = csr[beg + e];
      float4 a = as_v[s];
      float ah = sel_h(hd, a.x, a.y, a.z, a.w);
      float al = __expf(lrelu(ah + adh) - emh) * rdh;
      f16x8 v0 = *(const f16x8*)&Hh[(size_t)s * DHID + g * 16];
      f16x8 v1 = *(const f16x8*)&Hh[(size_t)s * DHID + g * 16 + 8];
#pragma unroll
      for (int q = 0; q < 8; ++q) acc[q] += al * (float)v0[q];
#pragma unroll
      for (int q = 0; q < 8; ++q) acc[8 + q] += al * (float)v1[q];
    }
  }

  const float* bv = &bias[g * 16];
  float* ob = &OUT[(size_t)n * DHID + g * 16];
#pragma unroll
  for (int k = 0; k < 4; ++k) {
    float4 b4 = *(const float4*)&bv[k * 4];
    *(float4*)&ob[k * 4] = make_float4(acc[k * 4] + b4.x, acc[k * 4 + 1] + b4.y,
                                       acc[k * 4 + 2] + b4.z, acc[k * 4 + 3] + b4.w);
  }
}

// ---------------- GAT aggregation, layer 2: one node per 16-lane group ----------------
__global__ __launch_bounds__(256) void k_agg2(const int* __restrict__ off, const int* __restrict__ csr,
                                              const float4* __restrict__ as_v, const float4* __restrict__ ad_v,
                                              const ushort_t* __restrict__ Hh, const float* __restrict__ bias,
                                              float* __restrict__ OUT) {
  __shared__ int s_tab[16][65];
  __shared__ __align__(16) float al_tab[16][260];
  const int tid = threadIdx.x;
  const int nd = tid >> 4;
  const int g = tid & 15;
  const int hd = g >> 2;
  const int n = blockIdx.x * 16 + nd;
  if (n >= NN) return;
  const int beg = off[n];
  const int nt = off[n + 1] - beg;
  const float4 adv = ad_v[n];

  float acc[8] = {};
  float rdh;

  if (nt <= 64) {
    float mx0 = -INFINITY, mx1 = -INFINITY, mx2 = -INFINITY, mx3 = -INFINITY;
    for (int le = g; le < nt; le += 16) {
      int s = csr[beg + le];
      float4 a = as_v[s];
      s_tab[nd][le] = s;
      *(float4*)&al_tab[nd][le << 2] = a;
      mx0 = fmaxf(mx0, a.x); mx1 = fmaxf(mx1, a.y);
      mx2 = fmaxf(mx2, a.z); mx3 = fmaxf(mx3, a.w);
    }
#pragma unroll
    for (int m = 1; m < 16; m <<= 1) {
      mx0 = fmaxf(mx0, __shfl_xor(mx0, m)); mx1 = fmaxf(mx1, __shfl_xor(mx1, m));
      mx2 = fmaxf(mx2, __shfl_xor(mx2, m)); mx3 = fmaxf(mx3, __shfl_xor(mx3, m));
    }
    float em0 = lrelu(mx0 + adv.x), em1 = lrelu(mx1 + adv.y);
    float em2 = lrelu(mx2 + adv.z), em3 = lrelu(mx3 + adv.w);
    float s0 = 0.f, s1 = 0.f, s2 = 0.f, s3 = 0.f;
    for (int le = g; le < nt; le += 16) {
      float4 a = *(const float4*)&al_tab[nd][le << 2];
      float p0 = __expf(lrelu(a.x + adv.x) - em0);
      float p1 = __expf(lrelu(a.y + adv.y) - em1);
      float p2 = __expf(lrelu(a.z + adv.z) - em2);
      float p3 = __expf(lrelu(a.w + adv.w) - em3);
      *(float4*)&al_tab[nd][le << 2] = make_float4(p0, p1, p2, p3);
      s0 += p0; s1 += p1; s2 += p2; s3 += p3;
    }
#pragma unroll
    for (int m = 1; m < 16; m <<= 1) {
      s0 += __shfl_xor(s0, m); s1 += __shfl_xor(s1, m);
      s2 += __shfl_xor(s2, m); s3 += __shfl_xor(s3, m);
    }
    rdh = sel_h(hd, 1.f / (s0 + 1e-16f), 1.f / (s1 + 1e-16f),
                    1.f / (s2 + 1e-16f), 1.f / (s3 + 1e-16f));

    int sP = s_tab[nd][0];
    float pP = al_tab[nd][hd];
    f16x8 v0 = *(const f16x8*)&Hh[(size_t)sP * DOUT + g * 8];
    for (int e = 0; e < nt; ++e) {
      int en = (e + 1 < nt) ? e + 1 : e;
      int sN = s_tab[nd][en];
      float pN = al_tab[nd][(en << 2) | hd];
      f16x8 n0 = *(const f16x8*)&Hh[(size_t)sN * DOUT + g * 8];
      float al = pP * rdh;
#pragma unroll
      for (int q = 0; q < 8; ++q) acc[q] += al * (float)v0[q];
      pP = pN; v0 = n0;
    }
  } else {
    float mx0 = -INFINITY, mx1 = -INFINITY, mx2 = -INFINITY, mx3 = -INFINITY;
    for (int le = g; le < nt; le += 16) {
      float4 a = as_v[csr[beg + le]];
      mx0 = fmaxf(mx0, a.x); mx1 = fmaxf(mx1, a.y);
      mx2 = fmaxf(mx2, a.z); mx3 = fmaxf(mx3, a.w);
    }
#pragma unroll
    for (int m = 1; m < 16; m <<= 1) {
      mx0 = fmaxf(mx0, __shfl_xor(mx0, m)); mx1 = fmaxf(mx1, __shfl_xor(mx1, m));
      mx2 = fmaxf(mx2, __shfl_xor(mx2, m)); mx3 = fmaxf(mx3, __shfl_xor(mx3, m));
    }
    float em0 = lrelu(mx0 + adv.x), em1 = lrelu(mx1 + adv.y);
    float em2 = lrelu(mx2 + adv.z), em3 = lrelu(mx3 + adv.w);
    float s0 = 0.f, s1 = 0.f, s2 = 0.f, s3 = 0.f;
    for (int le = g; le < nt; le += 16) {
      float4 a = as_v[csr[beg + le]];
      s0 += __expf(lrelu(a.x + adv.x) - em0);
      s1 += __expf(lrelu(a.y + adv.y) - em1);
      s2 += __expf(lrelu(a.z + adv.z) - em2);
      s3 += __expf(lrelu(a.w + adv.w) - em3);
    }
#pragma unroll
    for (int m = 1; m < 16; m <<= 1) {
      s0 += __shfl_xor(s0, m); s1 += __shfl_xor(s1, m);
      s2 += __shfl_xor(s2, m); s3 += __shfl_xor(s3, m);
    }
    rdh = sel_h(hd, 1.f / (s0 + 1e-16f), 1.f / (s1 + 1e-16f),
                    1.f / (s2 + 1e-16f), 1.f / (s3 + 1e-16f));
    float adh = sel_h(hd, adv.x, adv.y, adv.z, adv.w);
    float emh = sel_h(hd, em0, em1, em2, em3);
    for (int e = 0; e < nt; ++e) {
      int s = csr[beg + e];
      float4 a = as_v[s];
      float ah = sel_h(hd, a.x, a.y, a.z, a.w);
      float al = __expf(lrelu(ah + adh) - emh) * rdh;
      f16x8 v0 = *(const f16x8*)&Hh[(size_t)s * DOUT + g * 8];
#pragma unroll
      for (int q = 0; q < 8; ++q) acc[q] += al * (float)v0[q];
    }
  }

  const float* bv = &bias[g * 8];
  float* ob = &OUT[(size_t)n * DOUT + g * 8];
#pragma unroll
  for (int k = 0; k < 2; ++k) {
    float4 b4 = *(const float4*)&bv[k * 4];
    *(float4*)&ob[k * 4] = make_float4(acc[k * 4] + b4.x, acc[k * 4 + 1] + b4.y,
                                       acc[k * 4 + 2] + b4.z, acc[k * 4 + 3] + b4.w);
  }
}

// ---------------- pooling ----------------
__global__ __launch_bounds__(256) void k_pool(const int* __restrict__ segstart,
                                              const float* __restrict__ OUT2,
                                              const float* __restrict__ OUT1,
                                              float* __restrict__ out) {
  int b = blockIdx.x;
  int t = threadIdx.x;
  int s = segstart[b], e = segstart[b + 1];
  float* ob = out + (size_t)b * 384;
  if (s >= e) {
    for (int i = t; i < 384; i += 256) ob[i] = 0.f;
    return;
  }
  if (t < 128) {
    float s0 = 0.f, s1 = 0.f;
    int n = s;
    for (; n + 1 < e; n += 2) {
      float v0 = OUT2[(size_t)n * DOUT + t];
      float v1 = OUT2[(size_t)(n + 1) * DOUT + t];
      s0 += fmaxf(v0, 0.f); s1 += fmaxf(v1, 0.f);
    }
    if (n < e) s0 += fmaxf(OUT2[(size_t)n * DOUT + t], 0.f);
    ob[t] = (s0 + s1) / (float)(e - s);
  } else {
    int k = t - 128;
    ob[128 + k] = OUT1[(size_t)s * DHID + k];
    ob[256 + k] = OUT1[(size_t)s * DHID + 128 + k];
  }
}

// ---------------- launch ----------------
extern "C" void kernel_launch(void* const* d_in, const int* in_sizes, int n_in,
                              void* d_out, int out_size, void* d_ws, size_t ws_size,
                              hipStream_t stream) {
  const float* x    = (const float*)d_in[0];
  const int*   ei   = (const int*)d_in[1];
  const int*   batch = (const int*)d_in[2];
  const float* W1   = (const float*)d_in[3];
  const float* as1w = (const float*)d_in[4];
  const float* ad1w = (const float*)d_in[5];
  const float* b1   = (const float*)d_in[6];
  const float* W2   = (const float*)d_in[7];
  const float* as2w = (const float*)d_in[8];
  const float* ad2w = (const float*)d_in[9];
  const float* b2   = (const float*)d_in[10];
  float* out = (float*)d_out;
  char* ws = (char*)d_ws;

  const int E = in_sizes[1] / 2;
  const int Etot = E + NN;

  // workspace layout (bytes)
  ushort_t* H1h = (ushort_t*)(ws + 0);        // NN*256*2 = 25.6 MB (dead after agg1)
  ushort_t* H2h = (ushort_t*)(ws + 0);        // NN*128*2 (aliases H1h)
  ushort_t* Wt2b = (ushort_t*)(ws + 13000000);// 262144 B (written after agg1)
  float*  OUT2 = (float*)(ws + 25600000);
  float*  OUT1 = (float*)(ws + 51200000);
  float4* as1  = (float4*)(ws + 102400000);
  float4* ad1  = (float4*)(ws + 103200000);
  float4* as2  = (float4*)(ws + 104000000);
  float4* ad2  = (float4*)(ws + 104800000);
  int* deg     = (int*)(ws + 105600000);
  int* cur     = (int*)(ws + 105800000);
  int* off     = (int*)(ws + 106000000);
  int* csr     = (int*)(ws + 106200016);
  int* segstart = (int*)(ws + 109600016);
  int* rootn   = (int*)(ws + 109602080);
  int* bsum    = (int*)(ws + 109802080);
  ushort_t* Wt1b = (ushort_t*)(ws + 105600000);

  const int TB = 256;
  const int NB_SCAN = (NN + 1023) / 1024;

  k_zero2<<<(NN + TB - 1) / TB, TB, 0, stream>>>(deg, cur, NN);
  k_hist<<<(Etot + TB - 1) / TB, TB, 0, stream>>>(ei, deg, E, Etot);
  k_scan1<<<NB_SCAN, 1024, 0, stream>>>(deg, off, bsum, NN);
  k_scan2<<<1, 64, 0, stream>>>(bsum, off, NB_SCAN, NN);
  k_scan3<<<NB_SCAN, 1024, 0, stream>>>(off, bsum, NN);
  k_scatter<<<(Etot + TB - 1) / TB, TB, 0, stream>>>(ei, off, cur, csr, E, Etot);
  k_segstart<<<(NBGRAPH + 1 + TB - 1) / TB, TB, 0, stream>>>(batch, segstart, NN, NBGRAPH);
  k_rootn<<<(NN + TB - 1) / TB, TB, 0, stream>>>(batch, segstart, rootn, NN);

  k_prepW<<<(DIN * DHID + TB - 1) / TB, TB, 0, stream>>>(W1, Wt1b, DIN, DHID);
  dim3 g1((NN + 127) / 128, DHID / 128);
  k_gemm1m<<<g1, TB, 0, stream>>>(x, Wt1b, H1h);
  k_scores1<<<(NN + 3) / 4, TB, 0, stream>>>(H1h, as1w, ad1w, as1, ad1);
  k_agg1<<<(NN + 15) / 16, TB, 0, stream>>>(off, csr, as1, ad1, H1h, b1, OUT1);

  k_prepW<<<((DHID + DIN) * DOUT + TB - 1) / TB, TB, 0, stream>>>(W2, Wt2b, DHID + DIN, DOUT);
  dim3 g2((NN + 127) / 128, 1);
  k_gemm2m<<<g2, TB, 0, stream>>>(OUT1, x, rootn, Wt2b, H2h);
  k_scores2<<<(NN + 3) / 4, TB, 0, stream>>>(H2h, as2w, ad2w, as2, ad2);
  k_agg2<<<(NN + 15) / 16, TB, 0, stream>>>(off, csr, as2, ad2, H2h, b2, OUT2);

  k_pool<<<NBGRAPH, TB, 0, stream>>>(segstart, OUT2, OUT1, out);
}